// Round 1
// baseline (2415.516 us; speedup 1.0000x reference)
//
#include <hip/hip_runtime.h>
#include <math.h>

// Problem constants (from reference setup_inputs)
constexpr int N_NODES = 50000;
constexpr int E_EDGES = 800000;
constexpr int E_TOT   = E_EDGES + N_NODES;   // + self loops
constexpr int F_IN = 1433;
constexpr int F1 = 512;
constexpr int F2 = 256;
constexpr int NC = 7;
constexpr int MAXDEG = 1024;                 // Poisson(17) max ~45; huge margin
constexpr float NEG_SLOPE = 0.2f;

// ---------------------------------------------------------------------------
// CSR build: histogram -> exclusive scan -> scatter
// ---------------------------------------------------------------------------
__global__ void count_dst_kernel(const int* __restrict__ dst, int* __restrict__ counts) {
    int i = blockIdx.x * blockDim.x + threadIdx.x;
    if (i < E_TOT) {
        int d = (i < E_EDGES) ? dst[i] : (i - E_EDGES);
        atomicAdd(&counts[d], 1);
    }
}

// single-block exclusive scan over N counts -> row_ptr[0..N]
__global__ __launch_bounds__(1024) void scan_kernel(const int* __restrict__ counts,
                                                    int* __restrict__ row_ptr, int n) {
    __shared__ int part[1024];
    int t = threadIdx.x;
    int chunk = (n + 1023) / 1024;
    int lo = t * chunk;
    int hi = min(lo + chunk, n);
    int s = 0;
    for (int i = lo; i < hi; ++i) s += counts[i];
    part[t] = s;
    __syncthreads();
    // Hillis-Steele inclusive scan
    for (int off = 1; off < 1024; off <<= 1) {
        int v = 0;
        if (t >= off) v = part[t - off];
        __syncthreads();
        part[t] += v;
        __syncthreads();
    }
    int run = part[t] - s;  // exclusive base
    for (int i = lo; i < hi; ++i) { row_ptr[i] = run; run += counts[i]; }
    if (t == 1023) row_ptr[n] = part[1023];
}

__global__ void scatter_kernel(const int* __restrict__ src, const int* __restrict__ dst,
                               const int* __restrict__ row_ptr, int* __restrict__ fill,
                               int* __restrict__ col) {
    int i = blockIdx.x * blockDim.x + threadIdx.x;
    if (i < E_TOT) {
        int s = (i < E_EDGES) ? src[i] : (i - E_EDGES);
        int d = (i < E_EDGES) ? dst[i] : (i - E_EDGES);
        int p = row_ptr[d] + atomicAdd(&fill[d], 1);
        col[p] = s;
    }
}

// ---------------------------------------------------------------------------
// Tiled fp32 SGEMM: C[M,Nn] = A[M,K] @ B[K,Nn]; BM=BN=64, BK=16, 256 thr, 4x4
// A loads are scalar (K=1433 rows are not 16B aligned); B/C use float4.
// ---------------------------------------------------------------------------
__global__ __launch_bounds__(256) void sgemm_kernel(const float* __restrict__ A,
                                                    const float* __restrict__ B,
                                                    float* __restrict__ C,
                                                    int M, int Nn, int K) {
    constexpr int BM = 64, BN = 64, BK = 16;
    __shared__ float sA[BK][BM];   // transposed: sA[k][m]
    __shared__ float sB[BK][BN];
    int tid = threadIdx.x;
    int tx = tid & 15;     // n-tile
    int ty = tid >> 4;     // m-tile
    int m0 = blockIdx.y * BM;
    int n0 = blockIdx.x * BN;

    // A-load mapping: 4 scalars per thread
    int am = tid >> 2;             // 0..63
    int ak = (tid & 3) * 4;        // 0,4,8,12
    // B-load mapping: one float4 per thread
    int bk = tid >> 4;             // 0..15
    int bn = (tid & 15) * 4;

    bool mvalid = (m0 + am) < M;
    const float* arow = A + (size_t)(m0 + am) * K;

    float acc[4][4];
#pragma unroll
    for (int i = 0; i < 4; ++i)
#pragma unroll
        for (int j = 0; j < 4; ++j) acc[i][j] = 0.f;

    for (int k0 = 0; k0 < K; k0 += BK) {
        float a0 = 0.f, a1 = 0.f, a2 = 0.f, a3 = 0.f;
        if (mvalid) {
            int kb = k0 + ak;
            if (kb + 3 < K) {
                a0 = arow[kb]; a1 = arow[kb + 1]; a2 = arow[kb + 2]; a3 = arow[kb + 3];
            } else {
                if (kb + 0 < K) a0 = arow[kb + 0];
                if (kb + 1 < K) a1 = arow[kb + 1];
                if (kb + 2 < K) a2 = arow[kb + 2];
                if (kb + 3 < K) a3 = arow[kb + 3];
            }
        }
        sA[ak + 0][am] = a0; sA[ak + 1][am] = a1; sA[ak + 2][am] = a2; sA[ak + 3][am] = a3;

        float4 bv = make_float4(0.f, 0.f, 0.f, 0.f);
        if (k0 + bk < K) bv = *(const float4*)(B + (size_t)(k0 + bk) * Nn + n0 + bn);
        *(float4*)&sB[bk][bn] = bv;
        __syncthreads();

#pragma unroll
        for (int kk = 0; kk < BK; ++kk) {
            float av0 = sA[kk][ty * 4 + 0];
            float av1 = sA[kk][ty * 4 + 1];
            float av2 = sA[kk][ty * 4 + 2];
            float av3 = sA[kk][ty * 4 + 3];
            float4 b = *(const float4*)&sB[kk][tx * 4];
            acc[0][0] += av0 * b.x; acc[0][1] += av0 * b.y; acc[0][2] += av0 * b.z; acc[0][3] += av0 * b.w;
            acc[1][0] += av1 * b.x; acc[1][1] += av1 * b.y; acc[1][2] += av1 * b.z; acc[1][3] += av1 * b.w;
            acc[2][0] += av2 * b.x; acc[2][1] += av2 * b.y; acc[2][2] += av2 * b.z; acc[2][3] += av2 * b.w;
            acc[3][0] += av3 * b.x; acc[3][1] += av3 * b.y; acc[3][2] += av3 * b.z; acc[3][3] += av3 * b.w;
        }
        __syncthreads();
    }

#pragma unroll
    for (int i = 0; i < 4; ++i) {
        int m = m0 + ty * 4 + i;
        if (m < M) {
            float4 v = make_float4(acc[i][0], acc[i][1], acc[i][2], acc[i][3]);
            *(float4*)(C + (size_t)m * Nn + n0 + tx * 4) = v;
        }
    }
}

// ---------------------------------------------------------------------------
// Per-node attention scores: s_src[i] = h[i].a_src ; s_dst[i] = h[i].a_dst
// one wave per node
// ---------------------------------------------------------------------------
template <int F>
__global__ __launch_bounds__(256) void scores_kernel(const float* __restrict__ h,
                                                     const float* __restrict__ a_src,
                                                     const float* __restrict__ a_dst,
                                                     float* __restrict__ s_src,
                                                     float* __restrict__ s_dst, int n) {
    int gwid = (blockIdx.x * blockDim.x + threadIdx.x) >> 6;
    int lane = threadIdx.x & 63;
    if (gwid >= n) return;
    const float* row = h + (size_t)gwid * F;
    float acc1 = 0.f, acc2 = 0.f;
    for (int f = lane; f < F; f += 64) {
        float v = row[f];
        acc1 += v * a_src[f];
        acc2 += v * a_dst[f];
    }
#pragma unroll
    for (int o = 32; o; o >>= 1) {
        acc1 += __shfl_xor(acc1, o);
        acc2 += __shfl_xor(acc2, o);
    }
    if (lane == 0) { s_src[gwid] = acc1; s_dst[gwid] = acc2; }
}

// ---------------------------------------------------------------------------
// CSR aggregation with segment softmax. One block per destination node.
// Phase 1 (wave 0): e_j = leaky(s_src[col_j] + s_dst[i]); m = max; w_j = exp(e_j-m);
// denom = sum. Phase 2: out[i,f] = sum_j (w_j/denom) * h[col_j, f] + b[f]
// Optional fused ReLU, or fused log_softmax (layer 3, F=NC).
// ---------------------------------------------------------------------------
template <int F, int TPB, bool RELU, bool LSM>
__global__ __launch_bounds__(TPB) void aggregate_kernel(const float* __restrict__ h,
                                                        const float* __restrict__ s_src,
                                                        const float* __restrict__ s_dst,
                                                        const float* __restrict__ bias,
                                                        const int* __restrict__ row_ptr,
                                                        const int* __restrict__ col,
                                                        float* __restrict__ out) {
    constexpr int FPT = (F + TPB - 1) / TPB;
    int node = blockIdx.x;
    int tid = threadIdx.x;
    int beg = row_ptr[node];
    int deg = min(row_ptr[node + 1] - beg, MAXDEG);

    __shared__ float w[MAXDEG];
    __shared__ int cs[MAXDEG];
    __shared__ float sdenom;

    if (tid < 64) {
        float sd = s_dst[node];
        float m = -1e30f;
        for (int j = tid; j < deg; j += 64) {
            int s = col[beg + j];
            cs[j] = s;
            float e = s_src[s] + sd;
            e = (e > 0.f) ? e : NEG_SLOPE * e;
            w[j] = e;
            m = fmaxf(m, e);
        }
#pragma unroll
        for (int o = 32; o; o >>= 1) m = fmaxf(m, __shfl_xor(m, o));
        float sum = 0.f;
        for (int j = tid; j < deg; j += 64) {
            float v = expf(w[j] - m);
            w[j] = v;
            sum += v;
        }
#pragma unroll
        for (int o = 32; o; o >>= 1) sum += __shfl_xor(sum, o);
        if (tid == 0) sdenom = sum;
    }
    __syncthreads();
    float inv = 1.0f / sdenom;

    float acc[FPT];
#pragma unroll
    for (int r = 0; r < FPT; ++r) acc[r] = 0.f;

    for (int j = 0; j < deg; ++j) {
        float wgt = w[j] * inv;
        const float* row = h + (size_t)cs[j] * F;
#pragma unroll
        for (int r = 0; r < FPT; ++r) {
            int f = tid + r * TPB;
            if (f < F) acc[r] += wgt * row[f];
        }
    }

    if (!LSM) {
#pragma unroll
        for (int r = 0; r < FPT; ++r) {
            int f = tid + r * TPB;
            if (f < F) {
                float v = acc[r] + bias[f];
                if (RELU) v = fmaxf(v, 0.f);
                out[(size_t)node * F + f] = v;
            }
        }
    } else {
        // layer 3: fused log_softmax over F(=7) classes
        __shared__ float vals[F];
        if (tid < F) vals[tid] = acc[0] + bias[tid];
        __syncthreads();
        if (tid < F) {
            float mx = -1e30f;
#pragma unroll
            for (int i = 0; i < F; ++i) mx = fmaxf(mx, vals[i]);
            float ssum = 0.f;
#pragma unroll
            for (int i = 0; i < F; ++i) ssum += expf(vals[i] - mx);
            out[(size_t)node * F + tid] = vals[tid] - mx - logf(ssum);
        }
    }
}

// ---------------------------------------------------------------------------
// GEMM3: out[N,7] = A[N,256] @ W[256,7]. One wave per node, W staged in LDS.
// ---------------------------------------------------------------------------
__global__ __launch_bounds__(256) void gemm3_kernel(const float* __restrict__ A,
                                                    const float* __restrict__ W,
                                                    float* __restrict__ out, int n) {
    __shared__ float sW[F2 * NC];
    for (int i = threadIdx.x; i < F2 * NC; i += blockDim.x) sW[i] = W[i];
    __syncthreads();
    int gwid = (blockIdx.x * blockDim.x + threadIdx.x) >> 6;
    int lane = threadIdx.x & 63;
    if (gwid >= n) return;
    const float* row = A + (size_t)gwid * F2;
    float4 v = *(const float4*)(row + lane * 4);
    float res = 0.f;
#pragma unroll
    for (int c = 0; c < NC; ++c) {
        float p = v.x * sW[(lane * 4 + 0) * NC + c] + v.y * sW[(lane * 4 + 1) * NC + c] +
                  v.z * sW[(lane * 4 + 2) * NC + c] + v.w * sW[(lane * 4 + 3) * NC + c];
#pragma unroll
        for (int o = 32; o; o >>= 1) p += __shfl_xor(p, o);
        if (lane == c) res = p;
    }
    if (lane < NC) out[(size_t)gwid * NC + lane] = res;
}

// ---------------------------------------------------------------------------
extern "C" void kernel_launch(void* const* d_in, const int* in_sizes, int n_in,
                              void* d_out, int out_size, void* d_ws, size_t ws_size,
                              hipStream_t stream) {
    const float* x   = (const float*)d_in[0];
    const int* ei    = (const int*)d_in[1];
    const int* src   = ei;
    const int* dst   = ei + E_EDGES;
    const float* W1  = (const float*)d_in[2];
    const float* as1 = (const float*)d_in[3];
    const float* ad1 = (const float*)d_in[4];
    const float* b1  = (const float*)d_in[5];
    const float* W2  = (const float*)d_in[6];
    const float* as2 = (const float*)d_in[7];
    const float* ad2 = (const float*)d_in[8];
    const float* b2  = (const float*)d_in[9];
    const float* W3  = (const float*)d_in[10];
    const float* as3 = (const float*)d_in[11];
    const float* ad3 = (const float*)d_in[12];
    const float* b3  = (const float*)d_in[13];
    float* outp = (float*)d_out;

    // workspace layout (floats)
    float* ws = (float*)d_ws;
    const size_t N = N_NODES;
    float* h1 = ws;                       // N*512   (also reused for h2, h3)
    float* a1 = ws + N * F1;              // N*512   (also reused for a2)
    float* h2 = h1;                       // N*256  (GEMM2 reads a1, writes here)
    float* a2 = a1;                       // N*256  (agg2 reads h2, writes here)
    float* h3 = h1;                       // N*7    (GEMM3 reads a2, writes here)
    float* ssrc = ws + 2 * N * F1;        // N
    float* sdst = ssrc + N;               // N
    int* ip      = (int*)(sdst + N);
    int* row_ptr = ip;                    // N+1
    int* counts  = ip + (N_NODES + 1);    // N
    int* fill    = counts + N_NODES;      // N
    int* col     = fill + N_NODES;        // E_TOT

    hipMemsetAsync(counts, 0, sizeof(int) * N_NODES, stream);
    hipMemsetAsync(fill, 0, sizeof(int) * N_NODES, stream);

    // CSR build
    {
        int blk = 256;
        int grid = (E_TOT + blk - 1) / blk;
        count_dst_kernel<<<grid, blk, 0, stream>>>(dst, counts);
        scan_kernel<<<1, 1024, 0, stream>>>(counts, row_ptr, N_NODES);
        scatter_kernel<<<grid, blk, 0, stream>>>(src, dst, row_ptr, fill, col);
    }

    int waves_grid = (N_NODES + 3) / 4;  // 4 waves per 256-thread block

    // ---- Layer 1: x @ W1 -> h1 ; scores ; aggregate(+bias,+relu) -> a1
    {
        dim3 grid(F1 / 64, (N_NODES + 63) / 64);
        sgemm_kernel<<<grid, 256, 0, stream>>>(x, W1, h1, N_NODES, F1, F_IN);
        scores_kernel<F1><<<waves_grid, 256, 0, stream>>>(h1, as1, ad1, ssrc, sdst, N_NODES);
        aggregate_kernel<F1, 256, true, false><<<N_NODES, 256, 0, stream>>>(
            h1, ssrc, sdst, b1, row_ptr, col, a1);
    }
    // ---- Layer 2: a1 @ W2 -> h2 ; scores ; aggregate(+bias,+relu) -> a2
    {
        dim3 grid(F2 / 64, (N_NODES + 63) / 64);
        sgemm_kernel<<<grid, 256, 0, stream>>>(a1, W2, h2, N_NODES, F2, F1);
        scores_kernel<F2><<<waves_grid, 256, 0, stream>>>(h2, as2, ad2, ssrc, sdst, N_NODES);
        aggregate_kernel<F2, 256, true, false><<<N_NODES, 256, 0, stream>>>(
            h2, ssrc, sdst, b2, row_ptr, col, a2);
    }
    // ---- Layer 3: a2 @ W3 -> h3 ; scores ; aggregate(+bias) + log_softmax -> out
    {
        gemm3_kernel<<<waves_grid, 256, 0, stream>>>(a2, W3, h3, N_NODES);
        scores_kernel<NC><<<waves_grid, 256, 0, stream>>>(h3, as3, ad3, ssrc, sdst, N_NODES);
        aggregate_kernel<NC, 64, false, true><<<N_NODES, 64, 0, stream>>>(
            h3, ssrc, sdst, b3, row_ptr, col, outp);
    }
}

// Round 2
// 1126.603 us; speedup vs baseline: 2.1441x; 2.1441x over previous
//
#include <hip/hip_runtime.h>
#include <math.h>

// Problem constants (from reference setup_inputs)
constexpr int N_NODES = 50000;
constexpr int E_EDGES = 800000;
constexpr int E_TOT   = E_EDGES + N_NODES;   // + self loops
constexpr int F_IN  = 1433;
constexpr int KPAD1 = 1440;                  // F_IN padded to mult of 32
constexpr int F1 = 512;
constexpr int F2 = 256;
constexpr int NC = 7;
constexpr int MAXDEG = 1024;
constexpr float NEG_SLOPE = 0.2f;

typedef unsigned short u16;
typedef unsigned int   u32;
typedef short s16x8 __attribute__((ext_vector_type(8)));   // 8 bf16 = 4 VGPRs
typedef float f32x4 __attribute__((ext_vector_type(4)));

__device__ inline u16 f2b(float f) {                 // fp32 -> bf16 bits, RNE
    u32 u = __float_as_uint(f);
    u32 r = (u + 0x7fffu + ((u >> 16) & 1u)) >> 16;
    return (u16)r;
}
__device__ inline float b2f(u16 b) { return __uint_as_float(((u32)b) << 16); }

__device__ inline void gload_lds16(const void* g, void* l) {
    __builtin_amdgcn_global_load_lds(
        (const __attribute__((address_space(1))) u32*)g,
        (__attribute__((address_space(3))) u32*)l, 16, 0, 0);
}

// ---------------------------------------------------------------------------
// CSR build: histogram -> exclusive scan -> scatter
// ---------------------------------------------------------------------------
__global__ void count_dst_kernel(const int* __restrict__ dst, int* __restrict__ counts) {
    int i = blockIdx.x * blockDim.x + threadIdx.x;
    if (i < E_TOT) {
        int d = (i < E_EDGES) ? dst[i] : (i - E_EDGES);
        atomicAdd(&counts[d], 1);
    }
}

__global__ __launch_bounds__(1024) void scan_kernel(const int* __restrict__ counts,
                                                    int* __restrict__ row_ptr, int n) {
    __shared__ int part[1024];
    int t = threadIdx.x;
    int chunk = (n + 1023) / 1024;
    int lo = t * chunk;
    int hi = min(lo + chunk, n);
    int s = 0;
    for (int i = lo; i < hi; ++i) s += counts[i];
    part[t] = s;
    __syncthreads();
    for (int off = 1; off < 1024; off <<= 1) {
        int v = 0;
        if (t >= off) v = part[t - off];
        __syncthreads();
        part[t] += v;
        __syncthreads();
    }
    int run = part[t] - s;
    for (int i = lo; i < hi; ++i) { row_ptr[i] = run; run += counts[i]; }
    if (t == 1023) row_ptr[n] = part[1023];
}

__global__ void scatter_kernel(const int* __restrict__ src, const int* __restrict__ dst,
                               const int* __restrict__ row_ptr, int* __restrict__ fill,
                               int* __restrict__ col) {
    int i = blockIdx.x * blockDim.x + threadIdx.x;
    if (i < E_TOT) {
        int s = (i < E_EDGES) ? src[i] : (i - E_EDGES);
        int d = (i < E_EDGES) ? dst[i] : (i - E_EDGES);
        int p = row_ptr[d] + atomicAdd(&fill[d], 1);
        col[p] = s;
    }
}

// ---------------------------------------------------------------------------
// fp32 -> bf16 converts
// ---------------------------------------------------------------------------
// x [N][F_IN] f32 -> xb [N][KPAD1] bf16 (zero pad). One u32 (2 bf16) per thread.
__global__ void convert_x_kernel(const float* __restrict__ x, u32* __restrict__ xb) {
    constexpr int PPR = KPAD1 / 2;  // 720 pairs per row
    int p = blockIdx.x * blockDim.x + threadIdx.x;
    if (p >= N_NODES * PPR) return;
    int row = p / PPR;
    int c = (p - row * PPR) * 2;
    const float* xr = x + (size_t)row * F_IN;
    float v0 = (c + 0 < F_IN) ? xr[c + 0] : 0.f;
    float v1 = (c + 1 < F_IN) ? xr[c + 1] : 0.f;
    xb[p] = (u32)f2b(v0) | ((u32)f2b(v1) << 16);
}

// W [K][Nn] f32 -> Wt [Nn][KP] bf16 transposed (zero pad K)
__global__ void convert_wt_kernel(const float* __restrict__ W, u32* __restrict__ Wt,
                                  int K, int Nn, int KP) {
    int p = blockIdx.x * blockDim.x + threadIdx.x;
    int ppr = KP / 2;
    if (p >= Nn * ppr) return;
    int n = p / ppr;
    int k = (p - n * ppr) * 2;
    float v0 = (k + 0 < K) ? W[(size_t)(k + 0) * Nn + n] : 0.f;
    float v1 = (k + 1 < K) ? W[(size_t)(k + 1) * Nn + n] : 0.f;
    Wt[p] = (u32)f2b(v0) | ((u32)f2b(v1) << 16);
}

// ---------------------------------------------------------------------------
// MFMA bf16 GEMM: C[M][N] (bf16) = A[M][K] (bf16) @ Bt[N][K]^T (bf16)
// 128x128 tile, BK=32, 256 thr (4 waves in 2x2), 16x16x32 MFMA, 4x4 tiles/wave.
// global_load_lds width-16 staging; single-buffer 2-barrier K-loop (m97 style).
// ---------------------------------------------------------------------------
__global__ __launch_bounds__(256) void mfma_gemm_bt(const u16* __restrict__ A,
                                                    const u16* __restrict__ Bt,
                                                    u16* __restrict__ C,
                                                    int M, int N, int K) {
    __shared__ u16 sA[128 * 32];
    __shared__ u16 sB[128 * 32];
    int tid  = threadIdx.x;
    int wave = tid >> 6;
    int lane = tid & 63;
    int quad = lane >> 4;
    int lm   = lane & 15;
    int wm = wave & 1;
    int wn = wave >> 1;
    int m0 = blockIdx.y * 128;
    int n0 = blockIdx.x * 128;

    // staging: each wave fills 2 chunks of 1024B in sA and sB (16 rows each)
    int ch0 = wave * 2, ch1 = wave * 2 + 1;
    int rsub = lane >> 2;            // 0..15 row within chunk
    int csub = (lane & 3) * 8;       // bf16 col offset (8 elems = 16B)
    int ar0 = min(m0 + ch0 * 16 + rsub, M - 1);
    int ar1 = min(m0 + ch1 * 16 + rsub, M - 1);
    int br0 = n0 + ch0 * 16 + rsub;  // N is a multiple of 128
    int br1 = n0 + ch1 * 16 + rsub;
    const u16* gA0 = A + (size_t)ar0 * K + csub;
    const u16* gA1 = A + (size_t)ar1 * K + csub;
    const u16* gB0 = Bt + (size_t)br0 * K + csub;
    const u16* gB1 = Bt + (size_t)br1 * K + csub;

    f32x4 acc[4][4];
#pragma unroll
    for (int i = 0; i < 4; ++i)
#pragma unroll
        for (int j = 0; j < 4; ++j) acc[i][j] = (f32x4){0.f, 0.f, 0.f, 0.f};

    for (int k0 = 0; k0 < K; k0 += 32) {
        gload_lds16(gA0 + k0, &sA[ch0 * 512]);
        gload_lds16(gA1 + k0, &sA[ch1 * 512]);
        gload_lds16(gB0 + k0, &sB[ch0 * 512]);
        gload_lds16(gB1 + k0, &sB[ch1 * 512]);
        __syncthreads();   // drains vmcnt: staging visible

        s16x8 af[4], bf[4];
#pragma unroll
        for (int mt = 0; mt < 4; ++mt)
            af[mt] = *(const s16x8*)&sA[(wm * 64 + mt * 16 + lm) * 32 + quad * 8];
#pragma unroll
        for (int nt = 0; nt < 4; ++nt)
            bf[nt] = *(const s16x8*)&sB[(wn * 64 + nt * 16 + lm) * 32 + quad * 8];
#pragma unroll
        for (int mt = 0; mt < 4; ++mt)
#pragma unroll
            for (int nt = 0; nt < 4; ++nt)
                acc[mt][nt] = __builtin_amdgcn_mfma_f32_16x16x32_bf16(
                    af[mt], bf[nt], acc[mt][nt], 0, 0, 0);
        __syncthreads();   // all reads done before next stage overwrites
    }

    // C/D layout: col = lane&15 (N), row = quad*4 + reg (M)
#pragma unroll
    for (int mt = 0; mt < 4; ++mt) {
        int mbase = m0 + wm * 64 + mt * 16 + quad * 4;
#pragma unroll
        for (int nt = 0; nt < 4; ++nt) {
            int n = n0 + wn * 64 + nt * 16 + lm;
#pragma unroll
            for (int r = 0; r < 4; ++r) {
                int m = mbase + r;
                if (m < M) C[(size_t)m * N + n] = f2b(acc[mt][nt][r]);
            }
        }
    }
}

// ---------------------------------------------------------------------------
// Per-node attention scores, bf16 h. One wave per node.
// ---------------------------------------------------------------------------
template <int F>
__global__ __launch_bounds__(256) void scores_bf16_kernel(const u16* __restrict__ h,
                                                          const float* __restrict__ a_src,
                                                          const float* __restrict__ a_dst,
                                                          float* __restrict__ s_src,
                                                          float* __restrict__ s_dst, int n) {
    int gwid = (blockIdx.x * blockDim.x + threadIdx.x) >> 6;
    int lane = threadIdx.x & 63;
    if (gwid >= n) return;
    const u32* row = (const u32*)(h + (size_t)gwid * F);
    float acc1 = 0.f, acc2 = 0.f;
    for (int p = lane; p < F / 2; p += 64) {
        u32 u = row[p];
        float v0 = b2f((u16)(u & 0xffff));
        float v1 = b2f((u16)(u >> 16));
        acc1 += v0 * a_src[2 * p] + v1 * a_src[2 * p + 1];
        acc2 += v0 * a_dst[2 * p] + v1 * a_dst[2 * p + 1];
    }
#pragma unroll
    for (int o = 32; o; o >>= 1) {
        acc1 += __shfl_xor(acc1, o);
        acc2 += __shfl_xor(acc2, o);
    }
    if (lane == 0) { s_src[gwid] = acc1; s_dst[gwid] = acc2; }
}

// fp32 variant (layer 3, F=NC)
template <int F>
__global__ __launch_bounds__(256) void scores_kernel(const float* __restrict__ h,
                                                     const float* __restrict__ a_src,
                                                     const float* __restrict__ a_dst,
                                                     float* __restrict__ s_src,
                                                     float* __restrict__ s_dst, int n) {
    int gwid = (blockIdx.x * blockDim.x + threadIdx.x) >> 6;
    int lane = threadIdx.x & 63;
    if (gwid >= n) return;
    const float* row = h + (size_t)gwid * F;
    float acc1 = 0.f, acc2 = 0.f;
    for (int f = lane; f < F; f += 64) {
        float v = row[f];
        acc1 += v * a_src[f];
        acc2 += v * a_dst[f];
    }
#pragma unroll
    for (int o = 32; o; o >>= 1) {
        acc1 += __shfl_xor(acc1, o);
        acc2 += __shfl_xor(acc2, o);
    }
    if (lane == 0) { s_src[gwid] = acc1; s_dst[gwid] = acc2; }
}

// ---------------------------------------------------------------------------
// CSR aggregation + segment softmax, bf16 h input, relu fused.
// One block per destination node; TPB = F/2 threads handle bf16 pairs.
// ---------------------------------------------------------------------------
template <int F, bool OUT_BF16>
__global__ __launch_bounds__(F / 2) void agg_bf16_kernel(const u16* __restrict__ h,
                                                         const float* __restrict__ s_src,
                                                         const float* __restrict__ s_dst,
                                                         const float* __restrict__ bias,
                                                         const int* __restrict__ row_ptr,
                                                         const int* __restrict__ col,
                                                         void* __restrict__ out) {
    constexpr int TPB = F / 2;
    int node = blockIdx.x;
    int tid = threadIdx.x;
    int beg = row_ptr[node];
    int deg = min(row_ptr[node + 1] - beg, MAXDEG);

    __shared__ float w[MAXDEG];
    __shared__ int cs[MAXDEG];
    __shared__ float sdenom;

    if (tid < 64) {
        float sd = s_dst[node];
        float m = -1e30f;
        for (int j = tid; j < deg; j += 64) {
            int s = col[beg + j];
            cs[j] = s;
            float e = s_src[s] + sd;
            e = (e > 0.f) ? e : NEG_SLOPE * e;
            w[j] = e;
            m = fmaxf(m, e);
        }
#pragma unroll
        for (int o = 32; o; o >>= 1) m = fmaxf(m, __shfl_xor(m, o));
        float sum = 0.f;
        for (int j = tid; j < deg; j += 64) {
            float v = expf(w[j] - m);
            w[j] = v;
            sum += v;
        }
#pragma unroll
        for (int o = 32; o; o >>= 1) sum += __shfl_xor(sum, o);
        if (tid == 0) sdenom = sum;
    }
    __syncthreads();
    float inv = 1.0f / sdenom;

    float a0 = 0.f, a1 = 0.f;
    for (int j = 0; j < deg; ++j) {
        float wg = w[j] * inv;
        u32 u = ((const u32*)(h + (size_t)cs[j] * F))[tid];
        a0 += wg * b2f((u16)(u & 0xffff));
        a1 += wg * b2f((u16)(u >> 16));
    }
    float v0 = fmaxf(a0 + bias[2 * tid], 0.f);
    float v1 = fmaxf(a1 + bias[2 * tid + 1], 0.f);
    if (OUT_BF16) {
        ((u32*)out)[(size_t)node * TPB + tid] = (u32)f2b(v0) | ((u32)f2b(v1) << 16);
    } else {
        ((float2*)out)[(size_t)node * TPB + tid] = make_float2(v0, v1);
    }
}

// fp32 aggregation (layer 3) with fused log_softmax
template <int F, int TPB>
__global__ __launch_bounds__(TPB) void aggregate_lsm_kernel(const float* __restrict__ h,
                                                            const float* __restrict__ s_src,
                                                            const float* __restrict__ s_dst,
                                                            const float* __restrict__ bias,
                                                            const int* __restrict__ row_ptr,
                                                            const int* __restrict__ col,
                                                            float* __restrict__ out) {
    int node = blockIdx.x;
    int tid = threadIdx.x;
    int beg = row_ptr[node];
    int deg = min(row_ptr[node + 1] - beg, MAXDEG);

    __shared__ float w[MAXDEG];
    __shared__ int cs[MAXDEG];
    __shared__ float sdenom;

    if (tid < 64) {
        float sd = s_dst[node];
        float m = -1e30f;
        for (int j = tid; j < deg; j += 64) {
            int s = col[beg + j];
            cs[j] = s;
            float e = s_src[s] + sd;
            e = (e > 0.f) ? e : NEG_SLOPE * e;
            w[j] = e;
            m = fmaxf(m, e);
        }
#pragma unroll
        for (int o = 32; o; o >>= 1) m = fmaxf(m, __shfl_xor(m, o));
        float sum = 0.f;
        for (int j = tid; j < deg; j += 64) {
            float v = expf(w[j] - m);
            w[j] = v;
            sum += v;
        }
#pragma unroll
        for (int o = 32; o; o >>= 1) sum += __shfl_xor(sum, o);
        if (tid == 0) sdenom = sum;
    }
    __syncthreads();
    float inv = 1.0f / sdenom;

    float acc = 0.f;
    for (int j = 0; j < deg; ++j) {
        float wg = w[j] * inv;
        if (tid < F) acc += wg * h[(size_t)cs[j] * F + tid];
    }

    __shared__ float vals[F];
    if (tid < F) vals[tid] = acc + bias[tid];
    __syncthreads();
    if (tid < F) {
        float mx = -1e30f;
#pragma unroll
        for (int i = 0; i < F; ++i) mx = fmaxf(mx, vals[i]);
        float ssum = 0.f;
#pragma unroll
        for (int i = 0; i < F; ++i) ssum += expf(vals[i] - mx);
        out[(size_t)node * F + tid] = vals[tid] - mx - logf(ssum);
    }
}

// ---------------------------------------------------------------------------
// GEMM3: out[N,7] = A[N,256] f32 @ W[256,7] f32. One wave per node.
// ---------------------------------------------------------------------------
__global__ __launch_bounds__(256) void gemm3_kernel(const float* __restrict__ A,
                                                    const float* __restrict__ W,
                                                    float* __restrict__ out, int n) {
    __shared__ float sW[F2 * NC];
    for (int i = threadIdx.x; i < F2 * NC; i += blockDim.x) sW[i] = W[i];
    __syncthreads();
    int gwid = (blockIdx.x * blockDim.x + threadIdx.x) >> 6;
    int lane = threadIdx.x & 63;
    if (gwid >= n) return;
    const float* row = A + (size_t)gwid * F2;
    float4 v = *(const float4*)(row + lane * 4);
    float res = 0.f;
#pragma unroll
    for (int c = 0; c < NC; ++c) {
        float p = v.x * sW[(lane * 4 + 0) * NC + c] + v.y * sW[(lane * 4 + 1) * NC + c] +
                  v.z * sW[(lane * 4 + 2) * NC + c] + v.w * sW[(lane * 4 + 3) * NC + c];
#pragma unroll
        for (int o = 32; o; o >>= 1) p += __shfl_xor(p, o);
        if (lane == c) res = p;
    }
    if (lane < NC) out[(size_t)gwid * NC + lane] = res;
}

// ---------------------------------------------------------------------------
extern "C" void kernel_launch(void* const* d_in, const int* in_sizes, int n_in,
                              void* d_out, int out_size, void* d_ws, size_t ws_size,
                              hipStream_t stream) {
    const float* x   = (const float*)d_in[0];
    const int* ei    = (const int*)d_in[1];
    const int* src   = ei;
    const int* dst   = ei + E_EDGES;
    const float* W1  = (const float*)d_in[2];
    const float* as1 = (const float*)d_in[3];
    const float* ad1 = (const float*)d_in[4];
    const float* b1  = (const float*)d_in[5];
    const float* W2  = (const float*)d_in[6];
    const float* as2 = (const float*)d_in[7];
    const float* ad2 = (const float*)d_in[8];
    const float* b2  = (const float*)d_in[9];
    const float* W3  = (const float*)d_in[10];
    const float* as3 = (const float*)d_in[11];
    const float* ad3 = (const float*)d_in[12];
    const float* b3  = (const float*)d_in[13];
    float* outp = (float*)d_out;

    // ---------------- workspace layout (byte offsets; peak ~201 MB) --------
    char* base = (char*)d_ws;
    // R0 (144 MB): xb during layer-1 GEMM; then a1b / h2b / a2 / h3 overlay
    u16*  xb  = (u16*)base;                                   // [N][1440] bf16
    u16*  a1b = (u16*)base;                                   // [N][512]  bf16
    u16*  h2b = (u16*)(base + 51200000);                      // [N][256]  bf16
    float* a2 = (float*)(base + 76800000);                    // [N][256]  f32
    float* h3 = (float*)(base + 128000000);                   // [N][7]    f32
    // R1
    u16*  h1b = (u16*)(base + 144000000);                     // [N][512]  bf16
    u16*  W1t = (u16*)(base + 195200000);                     // [512][1440] bf16
    u16*  W2t = (u16*)(base + 196674560);                     // [256][512]  bf16
    float* ssrc = (float*)(base + 196936704);                 // [N]
    float* sdst = (float*)(base + 197136704);                 // [N]
    int* row_ptr = (int*)(base + 197336704);                  // [N+1]
    int* counts  = (int*)(base + 197536708);                  // [N]
    int* fill    = (int*)(base + 197736708);                  // [N]
    int* col     = (int*)(base + 197936708);                  // [E_TOT]

    hipMemsetAsync(counts, 0, sizeof(int) * N_NODES, stream);
    hipMemsetAsync(fill, 0, sizeof(int) * N_NODES, stream);

    // CSR build
    {
        int blk = 256;
        int grid = (E_TOT + blk - 1) / blk;
        count_dst_kernel<<<grid, blk, 0, stream>>>(dst, counts);
        scan_kernel<<<1, 1024, 0, stream>>>(counts, row_ptr, N_NODES);
        scatter_kernel<<<grid, blk, 0, stream>>>(src, dst, row_ptr, fill, col);
    }

    // bf16 conversions
    {
        int np = N_NODES * (KPAD1 / 2);
        convert_x_kernel<<<(np + 255) / 256, 256, 0, stream>>>(x, (u32*)xb);
        int nw1 = F1 * (KPAD1 / 2);
        convert_wt_kernel<<<(nw1 + 255) / 256, 256, 0, stream>>>(W1, (u32*)W1t, F_IN, F1, KPAD1);
        int nw2 = F2 * (F1 / 2);
        convert_wt_kernel<<<(nw2 + 255) / 256, 256, 0, stream>>>(W2, (u32*)W2t, F1, F2, F1);
    }

    int waves_grid = (N_NODES + 3) / 4;
    int mblocks = (N_NODES + 127) / 128;  // 391

    // ---- Layer 1
    {
        dim3 grid(F1 / 128, mblocks);
        mfma_gemm_bt<<<grid, 256, 0, stream>>>(xb, W1t, h1b, N_NODES, F1, KPAD1);
        scores_bf16_kernel<F1><<<waves_grid, 256, 0, stream>>>(h1b, as1, ad1, ssrc, sdst, N_NODES);
        agg_bf16_kernel<F1, true><<<N_NODES, F1 / 2, 0, stream>>>(
            h1b, ssrc, sdst, b1, row_ptr, col, a1b);
    }
    // ---- Layer 2
    {
        dim3 grid(F2 / 128, mblocks);
        mfma_gemm_bt<<<grid, 256, 0, stream>>>(a1b, W2t, h2b, N_NODES, F2, F1);
        scores_bf16_kernel<F2><<<waves_grid, 256, 0, stream>>>(h2b, as2, ad2, ssrc, sdst, N_NODES);
        agg_bf16_kernel<F2, false><<<N_NODES, F2 / 2, 0, stream>>>(
            h2b, ssrc, sdst, b2, row_ptr, col, a2);
    }
    // ---- Layer 3 (fp32)
    {
        gemm3_kernel<<<waves_grid, 256, 0, stream>>>(a2, W3, h3, N_NODES);
        scores_kernel<NC><<<waves_grid, 256, 0, stream>>>(h3, as3, ad3, ssrc, sdst, N_NODES);
        aggregate_lsm_kernel<NC, 64><<<N_NODES, 64, 0, stream>>>(
            h3, ssrc, sdst, b3, row_ptr, col, outp);
    }
}

// Round 3
// 1126.267 us; speedup vs baseline: 2.1447x; 1.0003x over previous
//
#include <hip/hip_runtime.h>
#include <math.h>

// Problem constants (from reference setup_inputs)
constexpr int N_NODES = 50000;
constexpr int E_EDGES = 800000;
constexpr int E_TOT   = E_EDGES + N_NODES;   // + self loops
constexpr int F_IN  = 1433;
constexpr int KPAD1 = 1440;                  // F_IN padded to mult of 32
constexpr int F1 = 512;
constexpr int F2 = 256;
constexpr int NC = 7;
constexpr int MAXDEG = 1024;
constexpr float NEG_SLOPE = 0.2f;

typedef unsigned short u16;
typedef unsigned int   u32;
typedef short s16x8 __attribute__((ext_vector_type(8)));   // 8 bf16 = 4 VGPRs
typedef float f32x4 __attribute__((ext_vector_type(4)));

__device__ inline u16 f2b(float f) {                 // fp32 -> bf16 bits, RNE
    u32 u = __float_as_uint(f);
    u32 r = (u + 0x7fffu + ((u >> 16) & 1u)) >> 16;
    return (u16)r;
}
__device__ inline float b2f(u16 b) { return __uint_as_float(((u32)b) << 16); }

__device__ inline void gload_lds16(const void* g, void* l) {
    __builtin_amdgcn_global_load_lds(
        (const __attribute__((address_space(1))) u32*)g,
        (__attribute__((address_space(3))) u32*)l, 16, 0, 0);
}

// ---------------------------------------------------------------------------
// CSR build: histogram -> exclusive scan -> scatter
// ---------------------------------------------------------------------------
__global__ void count_dst_kernel(const int* __restrict__ dst, int* __restrict__ counts) {
    int i = blockIdx.x * blockDim.x + threadIdx.x;
    if (i < E_TOT) {
        int d = (i < E_EDGES) ? dst[i] : (i - E_EDGES);
        atomicAdd(&counts[d], 1);
    }
}

__global__ __launch_bounds__(1024) void scan_kernel(const int* __restrict__ counts,
                                                    int* __restrict__ row_ptr, int n) {
    __shared__ int part[1024];
    int t = threadIdx.x;
    int chunk = (n + 1023) / 1024;
    int lo = t * chunk;
    int hi = min(lo + chunk, n);
    int s = 0;
    for (int i = lo; i < hi; ++i) s += counts[i];
    part[t] = s;
    __syncthreads();
    for (int off = 1; off < 1024; off <<= 1) {
        int v = 0;
        if (t >= off) v = part[t - off];
        __syncthreads();
        part[t] += v;
        __syncthreads();
    }
    int run = part[t] - s;
    for (int i = lo; i < hi; ++i) { row_ptr[i] = run; run += counts[i]; }
    if (t == 1023) row_ptr[n] = part[1023];
}

__global__ void scatter_kernel(const int* __restrict__ src, const int* __restrict__ dst,
                               const int* __restrict__ row_ptr, int* __restrict__ fill,
                               int* __restrict__ col) {
    int i = blockIdx.x * blockDim.x + threadIdx.x;
    if (i < E_TOT) {
        int s = (i < E_EDGES) ? src[i] : (i - E_EDGES);
        int d = (i < E_EDGES) ? dst[i] : (i - E_EDGES);
        int p = row_ptr[d] + atomicAdd(&fill[d], 1);
        col[p] = s;
    }
}

// ---------------------------------------------------------------------------
// fp32 -> bf16 converts
// ---------------------------------------------------------------------------
__global__ void convert_x_kernel(const float* __restrict__ x, u32* __restrict__ xb) {
    constexpr int PPR = KPAD1 / 2;  // 720 pairs per row
    int p = blockIdx.x * blockDim.x + threadIdx.x;
    if (p >= N_NODES * PPR) return;
    int row = p / PPR;
    int c = (p - row * PPR) * 2;
    const float* xr = x + (size_t)row * F_IN;
    float v0 = (c + 0 < F_IN) ? xr[c + 0] : 0.f;
    float v1 = (c + 1 < F_IN) ? xr[c + 1] : 0.f;
    xb[p] = (u32)f2b(v0) | ((u32)f2b(v1) << 16);
}

__global__ void convert_wt_kernel(const float* __restrict__ W, u32* __restrict__ Wt,
                                  int K, int Nn, int KP) {
    int p = blockIdx.x * blockDim.x + threadIdx.x;
    int ppr = KP / 2;
    if (p >= Nn * ppr) return;
    int n = p / ppr;
    int k = (p - n * ppr) * 2;
    float v0 = (k + 0 < K) ? W[(size_t)(k + 0) * Nn + n] : 0.f;
    float v1 = (k + 1 < K) ? W[(size_t)(k + 1) * Nn + n] : 0.f;
    Wt[p] = (u32)f2b(v0) | ((u32)f2b(v1) << 16);
}

// ---------------------------------------------------------------------------
// MFMA bf16 GEMM: C[M][N] (bf16) = A[M][K] (bf16) @ Bt[N][K]^T (bf16)
// ---------------------------------------------------------------------------
__global__ __launch_bounds__(256) void mfma_gemm_bt(const u16* __restrict__ A,
                                                    const u16* __restrict__ Bt,
                                                    u16* __restrict__ C,
                                                    int M, int N, int K) {
    __shared__ u16 sA[128 * 32];
    __shared__ u16 sB[128 * 32];
    int tid  = threadIdx.x;
    int wave = tid >> 6;
    int lane = tid & 63;
    int quad = lane >> 4;
    int lm   = lane & 15;
    int wm = wave & 1;
    int wn = wave >> 1;
    int m0 = blockIdx.y * 128;
    int n0 = blockIdx.x * 128;

    int ch0 = wave * 2, ch1 = wave * 2 + 1;
    int rsub = lane >> 2;
    int csub = (lane & 3) * 8;
    int ar0 = min(m0 + ch0 * 16 + rsub, M - 1);
    int ar1 = min(m0 + ch1 * 16 + rsub, M - 1);
    int br0 = n0 + ch0 * 16 + rsub;
    int br1 = n0 + ch1 * 16 + rsub;
    const u16* gA0 = A + (size_t)ar0 * K + csub;
    const u16* gA1 = A + (size_t)ar1 * K + csub;
    const u16* gB0 = Bt + (size_t)br0 * K + csub;
    const u16* gB1 = Bt + (size_t)br1 * K + csub;

    f32x4 acc[4][4];
#pragma unroll
    for (int i = 0; i < 4; ++i)
#pragma unroll
        for (int j = 0; j < 4; ++j) acc[i][j] = (f32x4){0.f, 0.f, 0.f, 0.f};

    for (int k0 = 0; k0 < K; k0 += 32) {
        gload_lds16(gA0 + k0, &sA[ch0 * 512]);
        gload_lds16(gA1 + k0, &sA[ch1 * 512]);
        gload_lds16(gB0 + k0, &sB[ch0 * 512]);
        gload_lds16(gB1 + k0, &sB[ch1 * 512]);
        __syncthreads();

        s16x8 af[4], bf[4];
#pragma unroll
        for (int mt = 0; mt < 4; ++mt)
            af[mt] = *(const s16x8*)&sA[(wm * 64 + mt * 16 + lm) * 32 + quad * 8];
#pragma unroll
        for (int nt = 0; nt < 4; ++nt)
            bf[nt] = *(const s16x8*)&sB[(wn * 64 + nt * 16 + lm) * 32 + quad * 8];
#pragma unroll
        for (int mt = 0; mt < 4; ++mt)
#pragma unroll
            for (int nt = 0; nt < 4; ++nt)
                acc[mt][nt] = __builtin_amdgcn_mfma_f32_16x16x32_bf16(
                    af[mt], bf[nt], acc[mt][nt], 0, 0, 0);
        __syncthreads();
    }

#pragma unroll
    for (int mt = 0; mt < 4; ++mt) {
        int mbase = m0 + wm * 64 + mt * 16 + quad * 4;
#pragma unroll
        for (int nt = 0; nt < 4; ++nt) {
            int n = n0 + wn * 64 + nt * 16 + lm;
#pragma unroll
            for (int r = 0; r < 4; ++r) {
                int m = mbase + r;
                if (m < M) C[(size_t)m * N + n] = f2b(acc[mt][nt][r]);
            }
        }
    }
}

// ---------------------------------------------------------------------------
// Per-node attention scores, bf16 h. One wave per node.
// ---------------------------------------------------------------------------
template <int F>
__global__ __launch_bounds__(256) void scores_bf16_kernel(const u16* __restrict__ h,
                                                          const float* __restrict__ a_src,
                                                          const float* __restrict__ a_dst,
                                                          float* __restrict__ s_src,
                                                          float* __restrict__ s_dst, int n) {
    int gwid = (blockIdx.x * blockDim.x + threadIdx.x) >> 6;
    int lane = threadIdx.x & 63;
    if (gwid >= n) return;
    const u32* row = (const u32*)(h + (size_t)gwid * F);
    float acc1 = 0.f, acc2 = 0.f;
    for (int p = lane; p < F / 2; p += 64) {
        u32 u = row[p];
        float v0 = b2f((u16)(u & 0xffff));
        float v1 = b2f((u16)(u >> 16));
        acc1 += v0 * a_src[2 * p] + v1 * a_src[2 * p + 1];
        acc2 += v0 * a_dst[2 * p] + v1 * a_dst[2 * p + 1];
    }
#pragma unroll
    for (int o = 32; o; o >>= 1) {
        acc1 += __shfl_xor(acc1, o);
        acc2 += __shfl_xor(acc2, o);
    }
    if (lane == 0) { s_src[gwid] = acc1; s_dst[gwid] = acc2; }
}

// fp32 variant (layer 3, F=NC)
template <int F>
__global__ __launch_bounds__(256) void scores_kernel(const float* __restrict__ h,
                                                     const float* __restrict__ a_src,
                                                     const float* __restrict__ a_dst,
                                                     float* __restrict__ s_src,
                                                     float* __restrict__ s_dst, int n) {
    int gwid = (blockIdx.x * blockDim.x + threadIdx.x) >> 6;
    int lane = threadIdx.x & 63;
    if (gwid >= n) return;
    const float* row = h + (size_t)gwid * F;
    float acc1 = 0.f, acc2 = 0.f;
    for (int f = lane; f < F; f += 64) {
        float v = row[f];
        acc1 += v * a_src[f];
        acc2 += v * a_dst[f];
    }
#pragma unroll
    for (int o = 32; o; o >>= 1) {
        acc1 += __shfl_xor(acc1, o);
        acc2 += __shfl_xor(acc2, o);
    }
    if (lane == 0) { s_src[gwid] = acc1; s_dst[gwid] = acc2; }
}

// ---------------------------------------------------------------------------
// CSR aggregation + segment softmax, bf16 h, wave-per-edge gather.
// 4 waves/block; wave w owns edges j = w, w+4, ... ; each lane loads
// 16B (F=512) / 8B (F=256) so one wave covers a full feature row per load.
// 2x manual unroll -> up to 8 row-loads in flight per block. Cross-wave
// reduction via LDS. Fused bias (+ReLU). OUT_BF16 picks output dtype.
// ---------------------------------------------------------------------------
template <int F, bool OUT_BF16>
__global__ __launch_bounds__(256) void agg_gather_kernel(const u16* __restrict__ h,
                                                         const float* __restrict__ s_src,
                                                         const float* __restrict__ s_dst,
                                                         const float* __restrict__ bias,
                                                         const int* __restrict__ row_ptr,
                                                         const int* __restrict__ col,
                                                         void* __restrict__ out) {
    constexpr int UPL = F / 128;   // u32 per lane: 4 (F=512) or 2 (F=256)
    int node = blockIdx.x;
    int tid = threadIdx.x;
    int wave = tid >> 6;
    int lane = tid & 63;
    int beg = row_ptr[node];
    int deg = min(row_ptr[node + 1] - beg, MAXDEG);

    __shared__ float w[MAXDEG];
    __shared__ int cs[MAXDEG];
    __shared__ float sdenom;
    __shared__ float red[4][F];

    if (wave == 0) {
        float sd = s_dst[node];
        float m = -1e30f;
        for (int j = lane; j < deg; j += 64) {
            int s = col[beg + j];
            cs[j] = s;
            float e = s_src[s] + sd;
            e = (e > 0.f) ? e : NEG_SLOPE * e;
            w[j] = e;
            m = fmaxf(m, e);
        }
#pragma unroll
        for (int o = 32; o; o >>= 1) m = fmaxf(m, __shfl_xor(m, o));
        float sum = 0.f;
        for (int j = lane; j < deg; j += 64) {
            float v = expf(w[j] - m);
            w[j] = v;
            sum += v;
        }
#pragma unroll
        for (int o = 32; o; o >>= 1) sum += __shfl_xor(sum, o);
        if (lane == 0) sdenom = sum;
    }
    __syncthreads();
    float inv = 1.0f / sdenom;

    float acc[2 * UPL];
#pragma unroll
    for (int e = 0; e < 2 * UPL; ++e) acc[e] = 0.f;

    int j = wave;
    for (; j + 4 < deg; j += 8) {
        float wg0 = w[j] * inv;
        float wg1 = w[j + 4] * inv;
        const u32* r0 = (const u32*)(h + (size_t)cs[j] * F) + lane * UPL;
        const u32* r1 = (const u32*)(h + (size_t)cs[j + 4] * F) + lane * UPL;
        u32 v0[UPL], v1[UPL];
        if constexpr (UPL == 4) {
            uint4 q0 = *(const uint4*)r0; v0[0] = q0.x; v0[1] = q0.y; v0[2] = q0.z; v0[3] = q0.w;
            uint4 q1 = *(const uint4*)r1; v1[0] = q1.x; v1[1] = q1.y; v1[2] = q1.z; v1[3] = q1.w;
        } else {
            uint2 q0 = *(const uint2*)r0; v0[0] = q0.x; v0[1] = q0.y;
            uint2 q1 = *(const uint2*)r1; v1[0] = q1.x; v1[1] = q1.y;
        }
#pragma unroll
        for (int u = 0; u < UPL; ++u) {
            acc[2 * u]     += wg0 * b2f((u16)(v0[u] & 0xffff)) + wg1 * b2f((u16)(v1[u] & 0xffff));
            acc[2 * u + 1] += wg0 * b2f((u16)(v0[u] >> 16))    + wg1 * b2f((u16)(v1[u] >> 16));
        }
    }
    if (j < deg) {
        float wg = w[j] * inv;
        const u32* r = (const u32*)(h + (size_t)cs[j] * F) + lane * UPL;
        u32 v[UPL];
        if constexpr (UPL == 4) {
            uint4 q = *(const uint4*)r; v[0] = q.x; v[1] = q.y; v[2] = q.z; v[3] = q.w;
        } else {
            uint2 q = *(const uint2*)r; v[0] = q.x; v[1] = q.y;
        }
#pragma unroll
        for (int u = 0; u < UPL; ++u) {
            acc[2 * u]     += wg * b2f((u16)(v[u] & 0xffff));
            acc[2 * u + 1] += wg * b2f((u16)(v[u] >> 16));
        }
    }

#pragma unroll
    for (int e = 0; e < 2 * UPL; ++e) red[wave][lane * 2 * UPL + e] = acc[e];
    __syncthreads();

    if constexpr (OUT_BF16) {
        if (tid < F / 2) {
            int f = tid * 2;
            float v0 = red[0][f] + red[1][f] + red[2][f] + red[3][f] + bias[f];
            float v1 = red[0][f + 1] + red[1][f + 1] + red[2][f + 1] + red[3][f + 1] + bias[f + 1];
            v0 = fmaxf(v0, 0.f);
            v1 = fmaxf(v1, 0.f);
            ((u32*)out)[(size_t)node * (F / 2) + tid] = (u32)f2b(v0) | ((u32)f2b(v1) << 16);
        }
    } else {
        if (tid < F) {
            float v = red[0][tid] + red[1][tid] + red[2][tid] + red[3][tid] + bias[tid];
            ((float*)out)[(size_t)node * F + tid] = fmaxf(v, 0.f);
        }
    }
}

// ---------------------------------------------------------------------------
// Layer-3 aggregation: lane-per-edge, 7 shuffle-reductions, fused log_softmax.
// One 64-thread block per node.
// ---------------------------------------------------------------------------
__global__ __launch_bounds__(64) void agg_lsm7_kernel(const float* __restrict__ h,
                                                      const float* __restrict__ s_src,
                                                      const float* __restrict__ s_dst,
                                                      const float* __restrict__ bias,
                                                      const int* __restrict__ row_ptr,
                                                      const int* __restrict__ col,
                                                      float* __restrict__ out) {
    int node = blockIdx.x;
    int lane = threadIdx.x;
    int beg = row_ptr[node];
    int deg = min(row_ptr[node + 1] - beg, MAXDEG);

    __shared__ float w[MAXDEG];
    __shared__ int cs[MAXDEG];

    float sd = s_dst[node];
    float m = -1e30f;
    for (int j = lane; j < deg; j += 64) {
        int s = col[beg + j];
        cs[j] = s;
        float e = s_src[s] + sd;
        e = (e > 0.f) ? e : NEG_SLOPE * e;
        w[j] = e;
        m = fmaxf(m, e);
    }
#pragma unroll
    for (int o = 32; o; o >>= 1) m = fmaxf(m, __shfl_xor(m, o));
    float sum = 0.f;
    for (int j = lane; j < deg; j += 64) {
        float v = expf(w[j] - m);
        w[j] = v;
        sum += v;
    }
#pragma unroll
    for (int o = 32; o; o >>= 1) sum += __shfl_xor(sum, o);
    float inv = 1.0f / sum;

    // single wave; each lane re-reads only the w[j]/cs[j] it wrote (same
    // stride-64 mapping) -> no barrier needed.
    float a[NC];
#pragma unroll
    for (int f = 0; f < NC; ++f) a[f] = 0.f;
    for (int j = lane; j < deg; j += 64) {
        float wg = w[j] * inv;
        const float* row = h + (size_t)cs[j] * NC;
#pragma unroll
        for (int f = 0; f < NC; ++f) a[f] += wg * row[f];
    }
#pragma unroll
    for (int f = 0; f < NC; ++f)
#pragma unroll
        for (int o = 32; o; o >>= 1) a[f] += __shfl_xor(a[f], o);

    if (lane == 0) {
        float vals[NC];
        float mx = -1e30f;
#pragma unroll
        for (int f = 0; f < NC; ++f) { vals[f] = a[f] + bias[f]; mx = fmaxf(mx, vals[f]); }
        float ssum = 0.f;
#pragma unroll
        for (int f = 0; f < NC; ++f) ssum += expf(vals[f] - mx);
        float lse = mx + logf(ssum);
#pragma unroll
        for (int f = 0; f < NC; ++f) out[(size_t)node * NC + f] = vals[f] - lse;
    }
}

// ---------------------------------------------------------------------------
// GEMM3: out[N,7] = A[N,256] f32 @ W[256,7] f32. One wave per node.
// ---------------------------------------------------------------------------
__global__ __launch_bounds__(256) void gemm3_kernel(const float* __restrict__ A,
                                                    const float* __restrict__ W,
                                                    float* __restrict__ out, int n) {
    __shared__ float sW[F2 * NC];
    for (int i = threadIdx.x; i < F2 * NC; i += blockDim.x) sW[i] = W[i];
    __syncthreads();
    int gwid = (blockIdx.x * blockDim.x + threadIdx.x) >> 6;
    int lane = threadIdx.x & 63;
    if (gwid >= n) return;
    const float* row = A + (size_t)gwid * F2;
    float4 v = *(const float4*)(row + lane * 4);
    float res = 0.f;
#pragma unroll
    for (int c = 0; c < NC; ++c) {
        float p = v.x * sW[(lane * 4 + 0) * NC + c] + v.y * sW[(lane * 4 + 1) * NC + c] +
                  v.z * sW[(lane * 4 + 2) * NC + c] + v.w * sW[(lane * 4 + 3) * NC + c];
#pragma unroll
        for (int o = 32; o; o >>= 1) p += __shfl_xor(p, o);
        if (lane == c) res = p;
    }
    if (lane < NC) out[(size_t)gwid * NC + lane] = res;
}

// ---------------------------------------------------------------------------
extern "C" void kernel_launch(void* const* d_in, const int* in_sizes, int n_in,
                              void* d_out, int out_size, void* d_ws, size_t ws_size,
                              hipStream_t stream) {
    const float* x   = (const float*)d_in[0];
    const int* ei    = (const int*)d_in[1];
    const int* src   = ei;
    const int* dst   = ei + E_EDGES;
    const float* W1  = (const float*)d_in[2];
    const float* as1 = (const float*)d_in[3];
    const float* ad1 = (const float*)d_in[4];
    const float* b1  = (const float*)d_in[5];
    const float* W2  = (const float*)d_in[6];
    const float* as2 = (const float*)d_in[7];
    const float* ad2 = (const float*)d_in[8];
    const float* b2  = (const float*)d_in[9];
    const float* W3  = (const float*)d_in[10];
    const float* as3 = (const float*)d_in[11];
    const float* ad3 = (const float*)d_in[12];
    const float* b3  = (const float*)d_in[13];
    float* outp = (float*)d_out;

    // ---------------- workspace layout (byte offsets; peak ~201 MB) --------
    char* base = (char*)d_ws;
    u16*  xb  = (u16*)base;                                   // [N][1440] bf16
    u16*  a1b = (u16*)base;                                   // [N][512]  bf16
    u16*  h2b = (u16*)(base + 51200000);                      // [N][256]  bf16
    float* a2 = (float*)(base + 76800000);                    // [N][256]  f32
    float* h3 = (float*)(base + 128000000);                   // [N][7]    f32
    u16*  h1b = (u16*)(base + 144000000);                     // [N][512]  bf16
    u16*  W1t = (u16*)(base + 195200000);                     // [512][1440] bf16
    u16*  W2t = (u16*)(base + 196674560);                     // [256][512]  bf16
    float* ssrc = (float*)(base + 196936704);                 // [N]
    float* sdst = (float*)(base + 197136704);                 // [N]
    int* row_ptr = (int*)(base + 197336704);                  // [N+1]
    int* counts  = (int*)(base + 197536708);                  // [N]
    int* fill    = (int*)(base + 197736708);                  // [N]
    int* col     = (int*)(base + 197936708);                  // [E_TOT]

    hipMemsetAsync(counts, 0, sizeof(int) * N_NODES, stream);
    hipMemsetAsync(fill, 0, sizeof(int) * N_NODES, stream);

    // CSR build
    {
        int blk = 256;
        int grid = (E_TOT + blk - 1) / blk;
        count_dst_kernel<<<grid, blk, 0, stream>>>(dst, counts);
        scan_kernel<<<1, 1024, 0, stream>>>(counts, row_ptr, N_NODES);
        scatter_kernel<<<grid, blk, 0, stream>>>(src, dst, row_ptr, fill, col);
    }

    // bf16 conversions
    {
        int np = N_NODES * (KPAD1 / 2);
        convert_x_kernel<<<(np + 255) / 256, 256, 0, stream>>>(x, (u32*)xb);
        int nw1 = F1 * (KPAD1 / 2);
        convert_wt_kernel<<<(nw1 + 255) / 256, 256, 0, stream>>>(W1, (u32*)W1t, F_IN, F1, KPAD1);
        int nw2 = F2 * (F1 / 2);
        convert_wt_kernel<<<(nw2 + 255) / 256, 256, 0, stream>>>(W2, (u32*)W2t, F1, F2, F1);
    }

    int waves_grid = (N_NODES + 3) / 4;
    int mblocks = (N_NODES + 127) / 128;  // 391

    // ---- Layer 1
    {
        dim3 grid(F1 / 128, mblocks);
        mfma_gemm_bt<<<grid, 256, 0, stream>>>(xb, W1t, h1b, N_NODES, F1, KPAD1);
        scores_bf16_kernel<F1><<<waves_grid, 256, 0, stream>>>(h1b, as1, ad1, ssrc, sdst, N_NODES);
        agg_gather_kernel<F1, true><<<N_NODES, 256, 0, stream>>>(
            h1b, ssrc, sdst, b1, row_ptr, col, a1b);
    }
    // ---- Layer 2
    {
        dim3 grid(F2 / 128, mblocks);
        mfma_gemm_bt<<<grid, 256, 0, stream>>>(a1b, W2t, h2b, N_NODES, F2, F1);
        scores_bf16_kernel<F2><<<waves_grid, 256, 0, stream>>>(h2b, as2, ad2, ssrc, sdst, N_NODES);
        agg_gather_kernel<F2, false><<<N_NODES, 256, 0, stream>>>(
            h2b, ssrc, sdst, b2, row_ptr, col, a2);
    }
    // ---- Layer 3 (fp32)
    {
        gemm3_kernel<<<waves_grid, 256, 0, stream>>>(a2, W3, h3, N_NODES);
        scores_kernel<NC><<<waves_grid, 256, 0, stream>>>(h3, as3, ad3, ssrc, sdst, N_NODES);
        agg_lsm7_kernel<<<N_NODES, 64, 0, stream>>>(
            h3, ssrc, sdst, b3, row_ptr, col, outp);
    }
}

// Round 4
// 1116.911 us; speedup vs baseline: 2.1627x; 1.0084x over previous
//
#include <hip/hip_runtime.h>
#include <hip/hip_bf16.h>
#include <math.h>

// Problem constants (from reference setup_inputs)
constexpr int N_NODES = 50000;
constexpr int E_EDGES = 800000;
constexpr int E_TOT   = E_EDGES + N_NODES;   // + self loops
constexpr int F_IN  = 1433;
constexpr int KPAD1 = 1440;                  // F_IN padded to mult of 32
constexpr int F1 = 512;
constexpr int F2 = 256;
constexpr int NC = 7;
constexpr int MAXDEG = 1024;
constexpr float NEG_SLOPE = 0.2f;

typedef unsigned short u16;
typedef unsigned int   u32;
typedef short s16x8 __attribute__((ext_vector_type(8)));   // 8 bf16 = 4 VGPRs
typedef u32   u32x4 __attribute__((ext_vector_type(4)));
typedef float f32x4 __attribute__((ext_vector_type(4)));

__device__ inline u16 f2b(float f) {                 // fp32 -> bf16 bits, RNE
    u32 u = __float_as_uint(f);
    u32 r = (u + 0x7fffu + ((u >> 16) & 1u)) >> 16;
    return (u16)r;
}
__device__ inline float b2f(u16 b) { return __uint_as_float(((u32)b) << 16); }

__device__ inline u32 pkbf16(float lo, float hi) {   // v_cvt_pk_bf16_f32 (RNE)
    union { __hip_bfloat162 h; u32 u; } c;
    c.h = __float22bfloat162_rn(make_float2(lo, hi));
    return c.u;
}

__device__ inline void gload_lds16(const void* g, void* l) {
    __builtin_amdgcn_global_load_lds(
        (const __attribute__((address_space(1))) u32*)g,
        (__attribute__((address_space(3))) u32*)l, 16, 0, 0);
}

// ---------------------------------------------------------------------------
// CSR build: histogram -> exclusive scan -> scatter
// ---------------------------------------------------------------------------
__global__ void count_dst_kernel(const int* __restrict__ dst, int* __restrict__ counts) {
    int i = blockIdx.x * blockDim.x + threadIdx.x;
    if (i < E_TOT) {
        int d = (i < E_EDGES) ? dst[i] : (i - E_EDGES);
        atomicAdd(&counts[d], 1);
    }
}

__global__ __launch_bounds__(1024) void scan_kernel(const int* __restrict__ counts,
                                                    int* __restrict__ row_ptr, int n) {
    __shared__ int part[1024];
    int t = threadIdx.x;
    int chunk = (n + 1023) / 1024;
    int lo = t * chunk;
    int hi = min(lo + chunk, n);
    int s = 0;
    for (int i = lo; i < hi; ++i) s += counts[i];
    part[t] = s;
    __syncthreads();
    for (int off = 1; off < 1024; off <<= 1) {
        int v = 0;
        if (t >= off) v = part[t - off];
        __syncthreads();
        part[t] += v;
        __syncthreads();
    }
    int run = part[t] - s;
    for (int i = lo; i < hi; ++i) { row_ptr[i] = run; run += counts[i]; }
    if (t == 1023) row_ptr[n] = part[1023];
}

__global__ void scatter_kernel(const int* __restrict__ src, const int* __restrict__ dst,
                               const int* __restrict__ row_ptr, int* __restrict__ fill,
                               int* __restrict__ col) {
    int i = blockIdx.x * blockDim.x + threadIdx.x;
    if (i < E_TOT) {
        int s = (i < E_EDGES) ? src[i] : (i - E_EDGES);
        int d = (i < E_EDGES) ? dst[i] : (i - E_EDGES);
        int p = row_ptr[d] + atomicAdd(&fill[d], 1);
        col[p] = s;
    }
}

// W [K][Nn] f32 -> Wt [Nn][KP] bf16 transposed (zero pad K)
__global__ void convert_wt_kernel(const float* __restrict__ W, u32* __restrict__ Wt,
                                  int K, int Nn, int KP) {
    int p = blockIdx.x * blockDim.x + threadIdx.x;
    int ppr = KP / 2;
    if (p >= Nn * ppr) return;
    int n = p / ppr;
    int k = (p - n * ppr) * 2;
    float v0 = (k + 0 < K) ? W[(size_t)(k + 0) * Nn + n] : 0.f;
    float v1 = (k + 1 < K) ? W[(size_t)(k + 1) * Nn + n] : 0.f;
    Wt[p] = (u32)f2b(v0) | ((u32)f2b(v1) << 16);
}

// ---------------------------------------------------------------------------
// Layer-1 MFMA GEMM with fused A conversion:
// C[M][N] (bf16) = A[M][Kf] (f32!) @ Bt[N][K32]^T (bf16, zero-padded k>=Kf)
// A staged to LDS as f32 (16 KB/step), converted to bf16 fragments in-register
// via v_cvt_pk_bf16_f32 (same RNE as f2b -> numerics identical to pre-convert).
// Last K-step peeled: A col addresses clamped in-bounds; B is zero there.
// ---------------------------------------------------------------------------
__global__ __launch_bounds__(256) void mfma_gemm_xf32(const float* __restrict__ A,
                                                      const u16* __restrict__ Bt,
                                                      u16* __restrict__ C,
                                                      int M, int N, int Kf, int K32) {
    __shared__ float sA[128 * 32];   // 16 KB: [row][k] row-major, stride 32
    __shared__ u16  sB[128 * 32];    // 8 KB
    int tid  = threadIdx.x;
    int wave = tid >> 6;
    int lane = tid & 63;
    int quad = lane >> 4;
    int lm   = lane & 15;
    int wm = wave & 1;
    int wn = wave >> 1;
    int m0 = blockIdx.y * 128;
    int n0 = blockIdx.x * 128;

    // A staging: 16 chunks x (8 rows x 32 f32 = 1KB). Wave w: chunks 4w..4w+3.
    // lane -> row (lane>>3), colf (lane&7)*4 within chunk.
    int arow_sub = lane >> 3;          // 0..7
    int acol     = (lane & 7) * 4;     // f32 col offset 0..28
    // B staging: 8 chunks x (16 rows x 32 bf16 = 1KB). Wave w: chunks 2w,2w+1.
    int brow_sub = lane >> 2;          // 0..15
    int bcol     = (lane & 3) * 8;     // bf16 col offset

    const float* gA[4];
    float* lA[4];
#pragma unroll
    for (int c = 0; c < 4; ++c) {
        int chunk = wave * 4 + c;
        int row = min(m0 + chunk * 8 + arow_sub, M - 1);
        gA[c] = A + (size_t)row * Kf + acol;
        lA[c] = &sA[chunk * 256];
    }
    const u16* gB[2];
    u16* lB[2];
#pragma unroll
    for (int c = 0; c < 2; ++c) {
        int chunk = wave * 2 + c;
        int row = n0 + chunk * 16 + brow_sub;   // N multiple of 128
        gB[c] = Bt + (size_t)row * K32 + bcol;
        lB[c] = &sB[chunk * 512];
    }

    f32x4 acc[4][4];
#pragma unroll
    for (int i = 0; i < 4; ++i)
#pragma unroll
        for (int j = 0; j < 4; ++j) acc[i][j] = (f32x4){0.f, 0.f, 0.f, 0.f};

    int kLast = K32 - 32;   // peeled final step
    for (int k0 = 0; k0 <= kLast; k0 += 32) {
        if (k0 < kLast) {
#pragma unroll
            for (int c = 0; c < 4; ++c) gload_lds16(gA[c] + k0, lA[c]);
        } else {
            // peel: clamp A columns in-bounds; B rows are zero for k>=Kf
            int colc = min(k0 + acol, Kf - 4);
#pragma unroll
            for (int c = 0; c < 4; ++c) gload_lds16(gA[c] - acol + colc, lA[c]);
        }
#pragma unroll
        for (int c = 0; c < 2; ++c) gload_lds16(gB[c] + k0, lB[c]);
        __syncthreads();

        s16x8 af[4], bf[4];
#pragma unroll
        for (int mt = 0; mt < 4; ++mt) {
            const float* pa = &sA[(wm * 64 + mt * 16 + lm) * 32 + quad * 8];
            float4 u0 = *(const float4*)pa;
            float4 u1 = *(const float4*)(pa + 4);
            u32x4 aw;
            aw[0] = pkbf16(u0.x, u0.y);
            aw[1] = pkbf16(u0.z, u0.w);
            aw[2] = pkbf16(u1.x, u1.y);
            aw[3] = pkbf16(u1.z, u1.w);
            af[mt] = __builtin_bit_cast(s16x8, aw);
        }
#pragma unroll
        for (int nt = 0; nt < 4; ++nt)
            bf[nt] = *(const s16x8*)&sB[(wn * 64 + nt * 16 + lm) * 32 + quad * 8];
#pragma unroll
        for (int mt = 0; mt < 4; ++mt)
#pragma unroll
            for (int nt = 0; nt < 4; ++nt)
                acc[mt][nt] = __builtin_amdgcn_mfma_f32_16x16x32_bf16(
                    af[mt], bf[nt], acc[mt][nt], 0, 0, 0);
        __syncthreads();
    }

#pragma unroll
    for (int mt = 0; mt < 4; ++mt) {
        int mbase = m0 + wm * 64 + mt * 16 + quad * 4;
#pragma unroll
        for (int nt = 0; nt < 4; ++nt) {
            int n = n0 + wn * 64 + nt * 16 + lm;
#pragma unroll
            for (int r = 0; r < 4; ++r) {
                int m = mbase + r;
                if (m < M) C[(size_t)m * N + n] = f2b(acc[mt][nt][r]);
            }
        }
    }
}

// ---------------------------------------------------------------------------
// MFMA bf16 GEMM (layer 2): C = A bf16 @ Bt^T
// ---------------------------------------------------------------------------
__global__ __launch_bounds__(256) void mfma_gemm_bt(const u16* __restrict__ A,
                                                    const u16* __restrict__ Bt,
                                                    u16* __restrict__ C,
                                                    int M, int N, int K) {
    __shared__ u16 sA[128 * 32];
    __shared__ u16 sB[128 * 32];
    int tid  = threadIdx.x;
    int wave = tid >> 6;
    int lane = tid & 63;
    int quad = lane >> 4;
    int lm   = lane & 15;
    int wm = wave & 1;
    int wn = wave >> 1;
    int m0 = blockIdx.y * 128;
    int n0 = blockIdx.x * 128;

    int ch0 = wave * 2, ch1 = wave * 2 + 1;
    int rsub = lane >> 2;
    int csub = (lane & 3) * 8;
    int ar0 = min(m0 + ch0 * 16 + rsub, M - 1);
    int ar1 = min(m0 + ch1 * 16 + rsub, M - 1);
    int br0 = n0 + ch0 * 16 + rsub;
    int br1 = n0 + ch1 * 16 + rsub;
    const u16* gA0 = A + (size_t)ar0 * K + csub;
    const u16* gA1 = A + (size_t)ar1 * K + csub;
    const u16* gB0 = Bt + (size_t)br0 * K + csub;
    const u16* gB1 = Bt + (size_t)br1 * K + csub;

    f32x4 acc[4][4];
#pragma unroll
    for (int i = 0; i < 4; ++i)
#pragma unroll
        for (int j = 0; j < 4; ++j) acc[i][j] = (f32x4){0.f, 0.f, 0.f, 0.f};

    for (int k0 = 0; k0 < K; k0 += 32) {
        gload_lds16(gA0 + k0, &sA[ch0 * 512]);
        gload_lds16(gA1 + k0, &sA[ch1 * 512]);
        gload_lds16(gB0 + k0, &sB[ch0 * 512]);
        gload_lds16(gB1 + k0, &sB[ch1 * 512]);
        __syncthreads();

        s16x8 af[4], bf[4];
#pragma unroll
        for (int mt = 0; mt < 4; ++mt)
            af[mt] = *(const s16x8*)&sA[(wm * 64 + mt * 16 + lm) * 32 + quad * 8];
#pragma unroll
        for (int nt = 0; nt < 4; ++nt)
            bf[nt] = *(const s16x8*)&sB[(wn * 64 + nt * 16 + lm) * 32 + quad * 8];
#pragma unroll
        for (int mt = 0; mt < 4; ++mt)
#pragma unroll
            for (int nt = 0; nt < 4; ++nt)
                acc[mt][nt] = __builtin_amdgcn_mfma_f32_16x16x32_bf16(
                    af[mt], bf[nt], acc[mt][nt], 0, 0, 0);
        __syncthreads();
    }

#pragma unroll
    for (int mt = 0; mt < 4; ++mt) {
        int mbase = m0 + wm * 64 + mt * 16 + quad * 4;
#pragma unroll
        for (int nt = 0; nt < 4; ++nt) {
            int n = n0 + wn * 64 + nt * 16 + lm;
#pragma unroll
            for (int r = 0; r < 4; ++r) {
                int m = mbase + r;
                if (m < M) C[(size_t)m * N + n] = f2b(acc[mt][nt][r]);
            }
        }
    }
}

// ---------------------------------------------------------------------------
// Per-node attention scores, bf16 h. One wave per node.
// ---------------------------------------------------------------------------
template <int F>
__global__ __launch_bounds__(256) void scores_bf16_kernel(const u16* __restrict__ h,
                                                          const float* __restrict__ a_src,
                                                          const float* __restrict__ a_dst,
                                                          float* __restrict__ s_src,
                                                          float* __restrict__ s_dst, int n) {
    int gwid = (blockIdx.x * blockDim.x + threadIdx.x) >> 6;
    int lane = threadIdx.x & 63;
    if (gwid >= n) return;
    const u32* row = (const u32*)(h + (size_t)gwid * F);
    float acc1 = 0.f, acc2 = 0.f;
    for (int p = lane; p < F / 2; p += 64) {
        u32 u = row[p];
        float v0 = b2f((u16)(u & 0xffff));
        float v1 = b2f((u16)(u >> 16));
        acc1 += v0 * a_src[2 * p] + v1 * a_src[2 * p + 1];
        acc2 += v0 * a_dst[2 * p] + v1 * a_dst[2 * p + 1];
    }
#pragma unroll
    for (int o = 32; o; o >>= 1) {
        acc1 += __shfl_xor(acc1, o);
        acc2 += __shfl_xor(acc2, o);
    }
    if (lane == 0) { s_src[gwid] = acc1; s_dst[gwid] = acc2; }
}

// fp32 variant (layer 3, F=NC)
template <int F>
__global__ __launch_bounds__(256) void scores_kernel(const float* __restrict__ h,
                                                     const float* __restrict__ a_src,
                                                     const float* __restrict__ a_dst,
                                                     float* __restrict__ s_src,
                                                     float* __restrict__ s_dst, int n) {
    int gwid = (blockIdx.x * blockDim.x + threadIdx.x) >> 6;
    int lane = threadIdx.x & 63;
    if (gwid >= n) return;
    const float* row = h + (size_t)gwid * F;
    float acc1 = 0.f, acc2 = 0.f;
    for (int f = lane; f < F; f += 64) {
        float v = row[f];
        acc1 += v * a_src[f];
        acc2 += v * a_dst[f];
    }
#pragma unroll
    for (int o = 32; o; o >>= 1) {
        acc1 += __shfl_xor(acc1, o);
        acc2 += __shfl_xor(acc2, o);
    }
    if (lane == 0) { s_src[gwid] = acc1; s_dst[gwid] = acc2; }
}

// ---------------------------------------------------------------------------
// CSR aggregation + segment softmax, bf16 h, wave-per-edge gather.
// ---------------------------------------------------------------------------
template <int F, bool OUT_BF16>
__global__ __launch_bounds__(256) void agg_gather_kernel(const u16* __restrict__ h,
                                                         const float* __restrict__ s_src,
                                                         const float* __restrict__ s_dst,
                                                         const float* __restrict__ bias,
                                                         const int* __restrict__ row_ptr,
                                                         const int* __restrict__ col,
                                                         void* __restrict__ out) {
    constexpr int UPL = F / 128;   // u32 per lane: 4 (F=512) or 2 (F=256)
    int node = blockIdx.x;
    int tid = threadIdx.x;
    int wave = tid >> 6;
    int lane = tid & 63;
    int beg = row_ptr[node];
    int deg = min(row_ptr[node + 1] - beg, MAXDEG);

    __shared__ float w[MAXDEG];
    __shared__ int cs[MAXDEG];
    __shared__ float sdenom;
    __shared__ float red[4][F];

    if (wave == 0) {
        float sd = s_dst[node];
        float m = -1e30f;
        for (int j = lane; j < deg; j += 64) {
            int s = col[beg + j];
            cs[j] = s;
            float e = s_src[s] + sd;
            e = (e > 0.f) ? e : NEG_SLOPE * e;
            w[j] = e;
            m = fmaxf(m, e);
        }
#pragma unroll
        for (int o = 32; o; o >>= 1) m = fmaxf(m, __shfl_xor(m, o));
        float sum = 0.f;
        for (int j = lane; j < deg; j += 64) {
            float v = expf(w[j] - m);
            w[j] = v;
            sum += v;
        }
#pragma unroll
        for (int o = 32; o; o >>= 1) sum += __shfl_xor(sum, o);
        if (lane == 0) sdenom = sum;
    }
    __syncthreads();
    float inv = 1.0f / sdenom;

    float acc[2 * UPL];
#pragma unroll
    for (int e = 0; e < 2 * UPL; ++e) acc[e] = 0.f;

    int j = wave;
    for (; j + 4 < deg; j += 8) {
        float wg0 = w[j] * inv;
        float wg1 = w[j + 4] * inv;
        const u32* r0 = (const u32*)(h + (size_t)cs[j] * F) + lane * UPL;
        const u32* r1 = (const u32*)(h + (size_t)cs[j + 4] * F) + lane * UPL;
        u32 v0[UPL], v1[UPL];
        if constexpr (UPL == 4) {
            uint4 q0 = *(const uint4*)r0; v0[0] = q0.x; v0[1] = q0.y; v0[2] = q0.z; v0[3] = q0.w;
            uint4 q1 = *(const uint4*)r1; v1[0] = q1.x; v1[1] = q1.y; v1[2] = q1.z; v1[3] = q1.w;
        } else {
            uint2 q0 = *(const uint2*)r0; v0[0] = q0.x; v0[1] = q0.y;
            uint2 q1 = *(const uint2*)r1; v1[0] = q1.x; v1[1] = q1.y;
        }
#pragma unroll
        for (int u = 0; u < UPL; ++u) {
            acc[2 * u]     += wg0 * b2f((u16)(v0[u] & 0xffff)) + wg1 * b2f((u16)(v1[u] & 0xffff));
            acc[2 * u + 1] += wg0 * b2f((u16)(v0[u] >> 16))    + wg1 * b2f((u16)(v1[u] >> 16));
        }
    }
    if (j < deg) {
        float wg = w[j] * inv;
        const u32* r = (const u32*)(h + (size_t)cs[j] * F) + lane * UPL;
        u32 v[UPL];
        if constexpr (UPL == 4) {
            uint4 q = *(const uint4*)r; v[0] = q.x; v[1] = q.y; v[2] = q.z; v[3] = q.w;
        } else {
            uint2 q = *(const uint2*)r; v[0] = q.x; v[1] = q.y;
        }
#pragma unroll
        for (int u = 0; u < UPL; ++u) {
            acc[2 * u]     += wg * b2f((u16)(v[u] & 0xffff));
            acc[2 * u + 1] += wg * b2f((u16)(v[u] >> 16));
        }
    }

#pragma unroll
    for (int e = 0; e < 2 * UPL; ++e) red[wave][lane * 2 * UPL + e] = acc[e];
    __syncthreads();

    if constexpr (OUT_BF16) {
        if (tid < F / 2) {
            int f = tid * 2;
            float v0 = red[0][f] + red[1][f] + red[2][f] + red[3][f] + bias[f];
            float v1 = red[0][f + 1] + red[1][f + 1] + red[2][f + 1] + red[3][f + 1] + bias[f + 1];
            v0 = fmaxf(v0, 0.f);
            v1 = fmaxf(v1, 0.f);
            ((u32*)out)[(size_t)node * (F / 2) + tid] = (u32)f2b(v0) | ((u32)f2b(v1) << 16);
        }
    } else {
        if (tid < F) {
            float v = red[0][tid] + red[1][tid] + red[2][tid] + red[3][tid] + bias[tid];
            ((float*)out)[(size_t)node * F + tid] = fmaxf(v, 0.f);
        }
    }
}

// ---------------------------------------------------------------------------
// Layer-3 aggregation: lane-per-edge, fused log_softmax. One wave per node.
// ---------------------------------------------------------------------------
__global__ __launch_bounds__(64) void agg_lsm7_kernel(const float* __restrict__ h,
                                                      const float* __restrict__ s_src,
                                                      const float* __restrict__ s_dst,
                                                      const float* __restrict__ bias,
                                                      const int* __restrict__ row_ptr,
                                                      const int* __restrict__ col,
                                                      float* __restrict__ out) {
    int node = blockIdx.x;
    int lane = threadIdx.x;
    int beg = row_ptr[node];
    int deg = min(row_ptr[node + 1] - beg, MAXDEG);

    __shared__ float w[MAXDEG];
    __shared__ int cs[MAXDEG];

    float sd = s_dst[node];
    float m = -1e30f;
    for (int j = lane; j < deg; j += 64) {
        int s = col[beg + j];
        cs[j] = s;
        float e = s_src[s] + sd;
        e = (e > 0.f) ? e : NEG_SLOPE * e;
        w[j] = e;
        m = fmaxf(m, e);
    }
#pragma unroll
    for (int o = 32; o; o >>= 1) m = fmaxf(m, __shfl_xor(m, o));
    float sum = 0.f;
    for (int j = lane; j < deg; j += 64) {
        float v = expf(w[j] - m);
        w[j] = v;
        sum += v;
    }
#pragma unroll
    for (int o = 32; o; o >>= 1) sum += __shfl_xor(sum, o);
    float inv = 1.0f / sum;

    float a[NC];
#pragma unroll
    for (int f = 0; f < NC; ++f) a[f] = 0.f;
    for (int j = lane; j < deg; j += 64) {
        float wg = w[j] * inv;
        const float* row = h + (size_t)cs[j] * NC;
#pragma unroll
        for (int f = 0; f < NC; ++f) a[f] += wg * row[f];
    }
#pragma unroll
    for (int f = 0; f < NC; ++f)
#pragma unroll
        for (int o = 32; o; o >>= 1) a[f] += __shfl_xor(a[f], o);

    if (lane == 0) {
        float vals[NC];
        float mx = -1e30f;
#pragma unroll
        for (int f = 0; f < NC; ++f) { vals[f] = a[f] + bias[f]; mx = fmaxf(mx, vals[f]); }
        float ssum = 0.f;
#pragma unroll
        for (int f = 0; f < NC; ++f) ssum += expf(vals[f] - mx);
        float lse = mx + logf(ssum);
#pragma unroll
        for (int f = 0; f < NC; ++f) out[(size_t)node * NC + f] = vals[f] - lse;
    }
}

// ---------------------------------------------------------------------------
// GEMM3: out[N,7] = A[N,256] f32 @ W[256,7] f32. One wave per node.
// ---------------------------------------------------------------------------
__global__ __launch_bounds__(256) void gemm3_kernel(const float* __restrict__ A,
                                                    const float* __restrict__ W,
                                                    float* __restrict__ out, int n) {
    __shared__ float sW[F2 * NC];
    for (int i = threadIdx.x; i < F2 * NC; i += blockDim.x) sW[i] = W[i];
    __syncthreads();
    int gwid = (blockIdx.x * blockDim.x + threadIdx.x) >> 6;
    int lane = threadIdx.x & 63;
    if (gwid >= n) return;
    const float* row = A + (size_t)gwid * F2;
    float4 v = *(const float4*)(row + lane * 4);
    float res = 0.f;
#pragma unroll
    for (int c = 0; c < NC; ++c) {
        float p = v.x * sW[(lane * 4 + 0) * NC + c] + v.y * sW[(lane * 4 + 1) * NC + c] +
                  v.z * sW[(lane * 4 + 2) * NC + c] + v.w * sW[(lane * 4 + 3) * NC + c];
#pragma unroll
        for (int o = 32; o; o >>= 1) p += __shfl_xor(p, o);
        if (lane == c) res = p;
    }
    if (lane < NC) out[(size_t)gwid * NC + lane] = res;
}

// ---------------------------------------------------------------------------
extern "C" void kernel_launch(void* const* d_in, const int* in_sizes, int n_in,
                              void* d_out, int out_size, void* d_ws, size_t ws_size,
                              hipStream_t stream) {
    const float* x   = (const float*)d_in[0];
    const int* ei    = (const int*)d_in[1];
    const int* src   = ei;
    const int* dst   = ei + E_EDGES;
    const float* W1  = (const float*)d_in[2];
    const float* as1 = (const float*)d_in[3];
    const float* ad1 = (const float*)d_in[4];
    const float* b1  = (const float*)d_in[5];
    const float* W2  = (const float*)d_in[6];
    const float* as2 = (const float*)d_in[7];
    const float* ad2 = (const float*)d_in[8];
    const float* b2  = (const float*)d_in[9];
    const float* W3  = (const float*)d_in[10];
    const float* as3 = (const float*)d_in[11];
    const float* ad3 = (const float*)d_in[12];
    const float* b3  = (const float*)d_in[13];
    float* outp = (float*)d_out;

    // ---------------- workspace layout (byte offsets) ----------------------
    char* base = (char*)d_ws;
    u16*  a1b = (u16*)base;                                   // [N][512]  bf16
    u16*  h2b = (u16*)(base + 51200000);                      // [N][256]  bf16
    float* a2 = (float*)(base + 76800000);                    // [N][256]  f32
    float* h3 = (float*)(base + 128000000);                   // [N][7]    f32
    u16*  h1b = (u16*)(base + 144000000);                     // [N][512]  bf16
    u16*  W1t = (u16*)(base + 195200000);                     // [512][1440] bf16
    u16*  W2t = (u16*)(base + 196674560);                     // [256][512]  bf16
    float* ssrc = (float*)(base + 196936704);                 // [N]
    float* sdst = (float*)(base + 197136704);                 // [N]
    int* row_ptr = (int*)(base + 197336704);                  // [N+1]
    int* counts  = (int*)(base + 197536708);                  // [N]
    int* fill    = (int*)(base + 197736708);                  // [N]
    int* col     = (int*)(base + 197936708);                  // [E_TOT]

    hipMemsetAsync(counts, 0, sizeof(int) * N_NODES, stream);
    hipMemsetAsync(fill, 0, sizeof(int) * N_NODES, stream);

    // CSR build
    {
        int blk = 256;
        int grid = (E_TOT + blk - 1) / blk;
        count_dst_kernel<<<grid, blk, 0, stream>>>(dst, counts);
        scan_kernel<<<1, 1024, 0, stream>>>(counts, row_ptr, N_NODES);
        scatter_kernel<<<grid, blk, 0, stream>>>(src, dst, row_ptr, fill, col);
    }

    // weight bf16 conversions (x conversion now fused into layer-1 GEMM)
    {
        int nw1 = F1 * (KPAD1 / 2);
        convert_wt_kernel<<<(nw1 + 255) / 256, 256, 0, stream>>>(W1, (u32*)W1t, F_IN, F1, KPAD1);
        int nw2 = F2 * (F1 / 2);
        convert_wt_kernel<<<(nw2 + 255) / 256, 256, 0, stream>>>(W2, (u32*)W2t, F1, F2, F1);
    }

    int waves_grid = (N_NODES + 3) / 4;
    int mblocks = (N_NODES + 127) / 128;  // 391

    // ---- Layer 1 (fused f32->bf16 A conversion inside GEMM)
    {
        dim3 grid(F1 / 128, mblocks);
        mfma_gemm_xf32<<<grid, 256, 0, stream>>>(x, W1t, h1b, N_NODES, F1, F_IN, KPAD1);
        scores_bf16_kernel<F1><<<waves_grid, 256, 0, stream>>>(h1b, as1, ad1, ssrc, sdst, N_NODES);
        agg_gather_kernel<F1, true><<<N_NODES, 256, 0, stream>>>(
            h1b, ssrc, sdst, b1, row_ptr, col, a1b);
    }
    // ---- Layer 2
    {
        dim3 grid(F2 / 128, mblocks);
        mfma_gemm_bt<<<grid, 256, 0, stream>>>(a1b, W2t, h2b, N_NODES, F2, F1);
        scores_bf16_kernel<F2><<<waves_grid, 256, 0, stream>>>(h2b, as2, ad2, ssrc, sdst, N_NODES);
        agg_gather_kernel<F2, false><<<N_NODES, 256, 0, stream>>>(
            h2b, ssrc, sdst, b2, row_ptr, col, a2);
    }
    // ---- Layer 3 (fp32)
    {
        gemm3_kernel<<<waves_grid, 256, 0, stream>>>(a2, W3, h3, N_NODES);
        scores_kernel<NC><<<waves_grid, 256, 0, stream>>>(h3, as3, ad3, ssrc, sdst, N_NODES);
        agg_lsm7_kernel<<<N_NODES, 64, 0, stream>>>(
            h3, ssrc, sdst, b3, row_ptr, col, outp);
    }
}

// Round 5
// 1085.928 us; speedup vs baseline: 2.2244x; 1.0285x over previous
//
#include <hip/hip_runtime.h>
#include <hip/hip_bf16.h>
#include <math.h>

// Problem constants (from reference setup_inputs)
constexpr int N_NODES = 50000;
constexpr int E_EDGES = 800000;
constexpr int E_TOT   = E_EDGES + N_NODES;   // + self loops
constexpr int F_IN  = 1433;
constexpr int KPAD1 = 1440;                  // F_IN padded to mult of 32
constexpr int F1 = 512;
constexpr int F2 = 256;
constexpr int NC = 7;
constexpr int MAXDEG = 1024;
constexpr float NEG_SLOPE = 0.2f;

typedef unsigned short u16;
typedef unsigned int   u32;
typedef short s16x8 __attribute__((ext_vector_type(8)));   // 8 bf16 = 4 VGPRs
typedef float f32x4 __attribute__((ext_vector_type(4)));

__device__ inline u16 f2b(float f) {                 // fp32 -> bf16 bits, RNE
    u32 u = __float_as_uint(f);
    u32 r = (u + 0x7fffu + ((u >> 16) & 1u)) >> 16;
    return (u16)r;
}
__device__ inline float b2f(u16 b) { return __uint_as_float(((u32)b) << 16); }

__device__ inline u32 pkbf16(float lo, float hi) {   // v_cvt_pk_bf16_f32 (RNE)
    union { __hip_bfloat162 h; u32 u; } c;
    c.h = __float22bfloat162_rn(make_float2(lo, hi));
    return c.u;
}

__device__ inline void gload_lds16(const void* g, void* l) {
    __builtin_amdgcn_global_load_lds(
        (const __attribute__((address_space(1))) u32*)g,
        (__attribute__((address_space(3))) u32*)l, 16, 0, 0);
}

// ---------------------------------------------------------------------------
// CSR build: histogram -> exclusive scan -> scatter
// ---------------------------------------------------------------------------
__global__ void count_dst_kernel(const int* __restrict__ dst, int* __restrict__ counts) {
    int i = blockIdx.x * blockDim.x + threadIdx.x;
    if (i < E_TOT) {
        int d = (i < E_EDGES) ? dst[i] : (i - E_EDGES);
        atomicAdd(&counts[d], 1);
    }
}

__global__ __launch_bounds__(1024) void scan_kernel(const int* __restrict__ counts,
                                                    int* __restrict__ row_ptr, int n) {
    __shared__ int part[1024];
    int t = threadIdx.x;
    int chunk = (n + 1023) / 1024;
    int lo = t * chunk;
    int hi = min(lo + chunk, n);
    int s = 0;
    for (int i = lo; i < hi; ++i) s += counts[i];
    part[t] = s;
    __syncthreads();
    for (int off = 1; off < 1024; off <<= 1) {
        int v = 0;
        if (t >= off) v = part[t - off];
        __syncthreads();
        part[t] += v;
        __syncthreads();
    }
    int run = part[t] - s;
    for (int i = lo; i < hi; ++i) { row_ptr[i] = run; run += counts[i]; }
    if (t == 1023) row_ptr[n] = part[1023];
}

__global__ void scatter_kernel(const int* __restrict__ src, const int* __restrict__ dst,
                               const int* __restrict__ row_ptr, int* __restrict__ fill,
                               int* __restrict__ col) {
    int i = blockIdx.x * blockDim.x + threadIdx.x;
    if (i < E_TOT) {
        int s = (i < E_EDGES) ? src[i] : (i - E_EDGES);
        int d = (i < E_EDGES) ? dst[i] : (i - E_EDGES);
        int p = row_ptr[d] + atomicAdd(&fill[d], 1);
        col[p] = s;
    }
}

// W [K][Nn] f32 -> Wt [Nn][KP] bf16 transposed (zero pad K)
__global__ void convert_wt_kernel(const float* __restrict__ W, u32* __restrict__ Wt,
                                  int K, int Nn, int KP) {
    int p = blockIdx.x * blockDim.x + threadIdx.x;
    int ppr = KP / 2;
    if (p >= Nn * ppr) return;
    int n = p / ppr;
    int k = (p - n * ppr) * 2;
    float v0 = (k + 0 < K) ? W[(size_t)(k + 0) * Nn + n] : 0.f;
    float v1 = (k + 1 < K) ? W[(size_t)(k + 1) * Nn + n] : 0.f;
    Wt[p] = (u32)f2b(v0) | ((u32)f2b(v1) << 16);
}

// ---------------------------------------------------------------------------
// Layer-1 fused GEMM: C[M][512](bf16) = A[M][1433](f32) @ W1t[512][1440]^T
// Tile 64(M) x 512(all of N) per block -> x is read from HBM exactly once.
// 4 waves, each owns 64x128 (acc 4x8 f32x4 = 128 VGPR). BK=32.
// A staged f32 via global_load_lds (8 KB), cvt phase packs to bf16 sAb (RNE,
// bit-identical to pre-converting). K-tail peeled with bounds-checked scalar
// loads (exact zero padding -- fixes R4's clamp-aliasing bug).
// ---------------------------------------------------------------------------
__global__ __launch_bounds__(256, 2) void gemm1_fused(const float* __restrict__ A,
                                                      const u16* __restrict__ Bt,
                                                      u16* __restrict__ C) {
    constexpr int M = N_NODES;
    __shared__ float sA32[64 * 32];   // 8 KB
    __shared__ u16  sAb[64 * 32];     // 4 KB
    __shared__ u16  sB[512 * 32];     // 32 KB
    int tid  = threadIdx.x;
    int wave = tid >> 6;
    int lane = tid & 63;
    int quad = lane >> 4;
    int lm   = lane & 15;
    int m0 = blockIdx.x * 64;

    // A staging: 8 chunks of (8 rows x 32 f32 = 1 KB); wave w: chunks 2w,2w+1
    const float* gA[2];
    float* lA[2];
#pragma unroll
    for (int c = 0; c < 2; ++c) {
        int chunk = wave * 2 + c;
        int row = min(m0 + chunk * 8 + (lane >> 3), M - 1);
        gA[c] = A + (size_t)row * F_IN + (lane & 7) * 4;
        lA[c] = &sA32[chunk * 256];
    }
    // B staging: 32 chunks of (16 rows x 32 bf16 = 1 KB); wave w: 8w..8w+7
    const u16* gB[8];
    u16* lB[8];
#pragma unroll
    for (int c = 0; c < 8; ++c) {
        int chunk = wave * 8 + c;
        int row = chunk * 16 + (lane >> 2);
        gB[c] = Bt + (size_t)row * KPAD1 + (lane & 3) * 8;
        lB[c] = &sB[chunk * 512];
    }

    f32x4 acc[4][8];
#pragma unroll
    for (int i = 0; i < 4; ++i)
#pragma unroll
        for (int j = 0; j < 8; ++j) acc[i][j] = (f32x4){0.f, 0.f, 0.f, 0.f};

    constexpr int K_MAIN = 1408;   // last full-in-bounds K step ends here
    for (int k0 = 0; k0 < K_MAIN; k0 += 32) {
#pragma unroll
        for (int c = 0; c < 2; ++c) gload_lds16(gA[c] + k0, lA[c]);
#pragma unroll
        for (int c = 0; c < 8; ++c) gload_lds16(gB[c] + k0, lB[c]);
        __syncthreads();

        // cvt phase: thread t packs f32 pairs (2t,2t+1)+512j  ->  sAb u32 t+256j
#pragma unroll
        for (int j = 0; j < 4; ++j) {
            float2 v = *(const float2*)&sA32[2 * tid + 512 * j];
            ((u32*)sAb)[tid + 256 * j] = pkbf16(v.x, v.y);
        }
        __syncthreads();

        s16x8 af[4], bf[8];
#pragma unroll
        for (int mt = 0; mt < 4; ++mt)
            af[mt] = *(const s16x8*)&sAb[(mt * 16 + lm) * 32 + quad * 8];
#pragma unroll
        for (int nt = 0; nt < 8; ++nt)
            bf[nt] = *(const s16x8*)&sB[(wave * 128 + nt * 16 + lm) * 32 + quad * 8];
#pragma unroll
        for (int mt = 0; mt < 4; ++mt)
#pragma unroll
            for (int nt = 0; nt < 8; ++nt)
                acc[mt][nt] = __builtin_amdgcn_mfma_f32_16x16x32_bf16(
                    af[mt], bf[nt], acc[mt][nt], 0, 0, 0);
        __syncthreads();
    }

    // ---- peeled tail k0 = 1408..1439 (A cols >= 1433 are exact zeros)
    {
        constexpr int k0 = K_MAIN;
#pragma unroll
        for (int c = 0; c < 8; ++c) gload_lds16(gB[c] + k0, lB[c]);  // W1t zero-padded
#pragma unroll
        for (int j = 0; j < 4; ++j) {
            int s = 2 * tid + 512 * j;      // f32 slot in 64x32
            int row = s >> 5;
            int gk = k0 + (s & 31);
            int ar = min(m0 + row, M - 1);
            const float* xr = A + (size_t)ar * F_IN;
            float v0 = (gk + 0 < F_IN) ? xr[gk + 0] : 0.f;
            float v1 = (gk + 1 < F_IN) ? xr[gk + 1] : 0.f;
            ((u32*)sAb)[tid + 256 * j] = pkbf16(v0, v1);
        }
        __syncthreads();

        s16x8 af[4], bf[8];
#pragma unroll
        for (int mt = 0; mt < 4; ++mt)
            af[mt] = *(const s16x8*)&sAb[(mt * 16 + lm) * 32 + quad * 8];
#pragma unroll
        for (int nt = 0; nt < 8; ++nt)
            bf[nt] = *(const s16x8*)&sB[(wave * 128 + nt * 16 + lm) * 32 + quad * 8];
#pragma unroll
        for (int mt = 0; mt < 4; ++mt)
#pragma unroll
            for (int nt = 0; nt < 8; ++nt)
                acc[mt][nt] = __builtin_amdgcn_mfma_f32_16x16x32_bf16(
                    af[mt], bf[nt], acc[mt][nt], 0, 0, 0);
    }

    // C write: col = lane&15, row = quad*4 + reg
#pragma unroll
    for (int mt = 0; mt < 4; ++mt) {
        int mbase = m0 + mt * 16 + quad * 4;
#pragma unroll
        for (int nt = 0; nt < 8; ++nt) {
            int n = wave * 128 + nt * 16 + lm;
#pragma unroll
            for (int r = 0; r < 4; ++r) {
                int m = mbase + r;
                if (m < M) C[(size_t)m * F1 + n] = f2b(acc[mt][nt][r]);
            }
        }
    }
}

// ---------------------------------------------------------------------------
// MFMA bf16 GEMM (layer 2): C = A bf16 @ Bt^T
// ---------------------------------------------------------------------------
__global__ __launch_bounds__(256) void mfma_gemm_bt(const u16* __restrict__ A,
                                                    const u16* __restrict__ Bt,
                                                    u16* __restrict__ C,
                                                    int M, int N, int K) {
    __shared__ u16 sA[128 * 32];
    __shared__ u16 sB[128 * 32];
    int tid  = threadIdx.x;
    int wave = tid >> 6;
    int lane = tid & 63;
    int quad = lane >> 4;
    int lm   = lane & 15;
    int wm = wave & 1;
    int wn = wave >> 1;
    int m0 = blockIdx.y * 128;
    int n0 = blockIdx.x * 128;

    int ch0 = wave * 2, ch1 = wave * 2 + 1;
    int rsub = lane >> 2;
    int csub = (lane & 3) * 8;
    int ar0 = min(m0 + ch0 * 16 + rsub, M - 1);
    int ar1 = min(m0 + ch1 * 16 + rsub, M - 1);
    int br0 = n0 + ch0 * 16 + rsub;
    int br1 = n0 + ch1 * 16 + rsub;
    const u16* gA0 = A + (size_t)ar0 * K + csub;
    const u16* gA1 = A + (size_t)ar1 * K + csub;
    const u16* gB0 = Bt + (size_t)br0 * K + csub;
    const u16* gB1 = Bt + (size_t)br1 * K + csub;

    f32x4 acc[4][4];
#pragma unroll
    for (int i = 0; i < 4; ++i)
#pragma unroll
        for (int j = 0; j < 4; ++j) acc[i][j] = (f32x4){0.f, 0.f, 0.f, 0.f};

    for (int k0 = 0; k0 < K; k0 += 32) {
        gload_lds16(gA0 + k0, &sA[ch0 * 512]);
        gload_lds16(gA1 + k0, &sA[ch1 * 512]);
        gload_lds16(gB0 + k0, &sB[ch0 * 512]);
        gload_lds16(gB1 + k0, &sB[ch1 * 512]);
        __syncthreads();

        s16x8 af[4], bf[4];
#pragma unroll
        for (int mt = 0; mt < 4; ++mt)
            af[mt] = *(const s16x8*)&sA[(wm * 64 + mt * 16 + lm) * 32 + quad * 8];
#pragma unroll
        for (int nt = 0; nt < 4; ++nt)
            bf[nt] = *(const s16x8*)&sB[(wn * 64 + nt * 16 + lm) * 32 + quad * 8];
#pragma unroll
        for (int mt = 0; mt < 4; ++mt)
#pragma unroll
            for (int nt = 0; nt < 4; ++nt)
                acc[mt][nt] = __builtin_amdgcn_mfma_f32_16x16x32_bf16(
                    af[mt], bf[nt], acc[mt][nt], 0, 0, 0);
        __syncthreads();
    }

#pragma unroll
    for (int mt = 0; mt < 4; ++mt) {
        int mbase = m0 + wm * 64 + mt * 16 + quad * 4;
#pragma unroll
        for (int nt = 0; nt < 4; ++nt) {
            int n = n0 + wn * 64 + nt * 16 + lm;
#pragma unroll
            for (int r = 0; r < 4; ++r) {
                int m = mbase + r;
                if (m < M) C[(size_t)m * N + n] = f2b(acc[mt][nt][r]);
            }
        }
    }
}

// ---------------------------------------------------------------------------
// Per-node attention scores, bf16 h. One wave per node.
// ---------------------------------------------------------------------------
template <int F>
__global__ __launch_bounds__(256) void scores_bf16_kernel(const u16* __restrict__ h,
                                                          const float* __restrict__ a_src,
                                                          const float* __restrict__ a_dst,
                                                          float* __restrict__ s_src,
                                                          float* __restrict__ s_dst, int n) {
    int gwid = (blockIdx.x * blockDim.x + threadIdx.x) >> 6;
    int lane = threadIdx.x & 63;
    if (gwid >= n) return;
    const u32* row = (const u32*)(h + (size_t)gwid * F);
    float acc1 = 0.f, acc2 = 0.f;
    for (int p = lane; p < F / 2; p += 64) {
        u32 u = row[p];
        float v0 = b2f((u16)(u & 0xffff));
        float v1 = b2f((u16)(u >> 16));
        acc1 += v0 * a_src[2 * p] + v1 * a_src[2 * p + 1];
        acc2 += v0 * a_dst[2 * p] + v1 * a_dst[2 * p + 1];
    }
#pragma unroll
    for (int o = 32; o; o >>= 1) {
        acc1 += __shfl_xor(acc1, o);
        acc2 += __shfl_xor(acc2, o);
    }
    if (lane == 0) { s_src[gwid] = acc1; s_dst[gwid] = acc2; }
}

// fp32 variant (layer 3, F=NC)
template <int F>
__global__ __launch_bounds__(256) void scores_kernel(const float* __restrict__ h,
                                                     const float* __restrict__ a_src,
                                                     const float* __restrict__ a_dst,
                                                     float* __restrict__ s_src,
                                                     float* __restrict__ s_dst, int n) {
    int gwid = (blockIdx.x * blockDim.x + threadIdx.x) >> 6;
    int lane = threadIdx.x & 63;
    if (gwid >= n) return;
    const float* row = h + (size_t)gwid * F;
    float acc1 = 0.f, acc2 = 0.f;
    for (int f = lane; f < F; f += 64) {
        float v = row[f];
        acc1 += v * a_src[f];
        acc2 += v * a_dst[f];
    }
#pragma unroll
    for (int o = 32; o; o >>= 1) {
        acc1 += __shfl_xor(acc1, o);
        acc2 += __shfl_xor(acc2, o);
    }
    if (lane == 0) { s_src[gwid] = acc1; s_dst[gwid] = acc2; }
}

// ---------------------------------------------------------------------------
// CSR aggregation + segment softmax, bf16 h, wave-per-edge gather.
// ---------------------------------------------------------------------------
template <int F, bool OUT_BF16>
__global__ __launch_bounds__(256) void agg_gather_kernel(const u16* __restrict__ h,
                                                         const float* __restrict__ s_src,
                                                         const float* __restrict__ s_dst,
                                                         const float* __restrict__ bias,
                                                         const int* __restrict__ row_ptr,
                                                         const int* __restrict__ col,
                                                         void* __restrict__ out) {
    constexpr int UPL = F / 128;   // u32 per lane: 4 (F=512) or 2 (F=256)
    int node = blockIdx.x;
    int tid = threadIdx.x;
    int wave = tid >> 6;
    int lane = tid & 63;
    int beg = row_ptr[node];
    int deg = min(row_ptr[node + 1] - beg, MAXDEG);

    __shared__ float w[MAXDEG];
    __shared__ int cs[MAXDEG];
    __shared__ float sdenom;
    __shared__ float red[4][F];

    if (wave == 0) {
        float sd = s_dst[node];
        float m = -1e30f;
        for (int j = lane; j < deg; j += 64) {
            int s = col[beg + j];
            cs[j] = s;
            float e = s_src[s] + sd;
            e = (e > 0.f) ? e : NEG_SLOPE * e;
            w[j] = e;
            m = fmaxf(m, e);
        }
#pragma unroll
        for (int o = 32; o; o >>= 1) m = fmaxf(m, __shfl_xor(m, o));
        float sum = 0.f;
        for (int j = lane; j < deg; j += 64) {
            float v = expf(w[j] - m);
            w[j] = v;
            sum += v;
        }
#pragma unroll
        for (int o = 32; o; o >>= 1) sum += __shfl_xor(sum, o);
        if (lane == 0) sdenom = sum;
    }
    __syncthreads();
    float inv = 1.0f / sdenom;

    float acc[2 * UPL];
#pragma unroll
    for (int e = 0; e < 2 * UPL; ++e) acc[e] = 0.f;

    int j = wave;
    for (; j + 4 < deg; j += 8) {
        float wg0 = w[j] * inv;
        float wg1 = w[j + 4] * inv;
        const u32* r0 = (const u32*)(h + (size_t)cs[j] * F) + lane * UPL;
        const u32* r1 = (const u32*)(h + (size_t)cs[j + 4] * F) + lane * UPL;
        u32 v0[UPL], v1[UPL];
        if constexpr (UPL == 4) {
            uint4 q0 = *(const uint4*)r0; v0[0] = q0.x; v0[1] = q0.y; v0[2] = q0.z; v0[3] = q0.w;
            uint4 q1 = *(const uint4*)r1; v1[0] = q1.x; v1[1] = q1.y; v1[2] = q1.z; v1[3] = q1.w;
        } else {
            uint2 q0 = *(const uint2*)r0; v0[0] = q0.x; v0[1] = q0.y;
            uint2 q1 = *(const uint2*)r1; v1[0] = q1.x; v1[1] = q1.y;
        }
#pragma unroll
        for (int u = 0; u < UPL; ++u) {
            acc[2 * u]     += wg0 * b2f((u16)(v0[u] & 0xffff)) + wg1 * b2f((u16)(v1[u] & 0xffff));
            acc[2 * u + 1] += wg0 * b2f((u16)(v0[u] >> 16))    + wg1 * b2f((u16)(v1[u] >> 16));
        }
    }
    if (j < deg) {
        float wg = w[j] * inv;
        const u32* r = (const u32*)(h + (size_t)cs[j] * F) + lane * UPL;
        u32 v[UPL];
        if constexpr (UPL == 4) {
            uint4 q = *(const uint4*)r; v[0] = q.x; v[1] = q.y; v[2] = q.z; v[3] = q.w;
        } else {
            uint2 q = *(const uint2*)r; v[0] = q.x; v[1] = q.y;
        }
#pragma unroll
        for (int u = 0; u < UPL; ++u) {
            acc[2 * u]     += wg * b2f((u16)(v[u] & 0xffff));
            acc[2 * u + 1] += wg * b2f((u16)(v[u] >> 16));
        }
    }

#pragma unroll
    for (int e = 0; e < 2 * UPL; ++e) red[wave][lane * 2 * UPL + e] = acc[e];
    __syncthreads();

    if constexpr (OUT_BF16) {
        if (tid < F / 2) {
            int f = tid * 2;
            float v0 = red[0][f] + red[1][f] + red[2][f] + red[3][f] + bias[f];
            float v1 = red[0][f + 1] + red[1][f + 1] + red[2][f + 1] + red[3][f + 1] + bias[f + 1];
            v0 = fmaxf(v0, 0.f);
            v1 = fmaxf(v1, 0.f);
            ((u32*)out)[(size_t)node * (F / 2) + tid] = (u32)f2b(v0) | ((u32)f2b(v1) << 16);
        }
    } else {
        if (tid < F) {
            float v = red[0][tid] + red[1][tid] + red[2][tid] + red[3][tid] + bias[tid];
            ((float*)out)[(size_t)node * F + tid] = fmaxf(v, 0.f);
        }
    }
}

// ---------------------------------------------------------------------------
// Layer-3 aggregation: lane-per-edge, fused log_softmax. One wave per node.
// ---------------------------------------------------------------------------
__global__ __launch_bounds__(64) void agg_lsm7_kernel(const float* __restrict__ h,
                                                      const float* __restrict__ s_src,
                                                      const float* __restrict__ s_dst,
                                                      const float* __restrict__ bias,
                                                      const int* __restrict__ row_ptr,
                                                      const int* __restrict__ col,
                                                      float* __restrict__ out) {
    int node = blockIdx.x;
    int lane = threadIdx.x;
    int beg = row_ptr[node];
    int deg = min(row_ptr[node + 1] - beg, MAXDEG);

    __shared__ float w[MAXDEG];
    __shared__ int cs[MAXDEG];

    float sd = s_dst[node];
    float m = -1e30f;
    for (int j = lane; j < deg; j += 64) {
        int s = col[beg + j];
        cs[j] = s;
        float e = s_src[s] + sd;
        e = (e > 0.f) ? e : NEG_SLOPE * e;
        w[j] = e;
        m = fmaxf(m, e);
    }
#pragma unroll
    for (int o = 32; o; o >>= 1) m = fmaxf(m, __shfl_xor(m, o));
    float sum = 0.f;
    for (int j = lane; j < deg; j += 64) {
        float v = expf(w[j] - m);
        w[j] = v;
        sum += v;
    }
#pragma unroll
    for (int o = 32; o; o >>= 1) sum += __shfl_xor(sum, o);
    float inv = 1.0f / sum;

    float a[NC];
#pragma unroll
    for (int f = 0; f < NC; ++f) a[f] = 0.f;
    for (int j = lane; j < deg; j += 64) {
        float wg = w[j] * inv;
        const float* row = h + (size_t)cs[j] * NC;
#pragma unroll
        for (int f = 0; f < NC; ++f) a[f] += wg * row[f];
    }
#pragma unroll
    for (int f = 0; f < NC; ++f)
#pragma unroll
        for (int o = 32; o; o >>= 1) a[f] += __shfl_xor(a[f], o);

    if (lane == 0) {
        float vals[NC];
        float mx = -1e30f;
#pragma unroll
        for (int f = 0; f < NC; ++f) { vals[f] = a[f] + bias[f]; mx = fmaxf(mx, vals[f]); }
        float ssum = 0.f;
#pragma unroll
        for (int f = 0; f < NC; ++f) ssum += expf(vals[f] - mx);
        float lse = mx + logf(ssum);
#pragma unroll
        for (int f = 0; f < NC; ++f) out[(size_t)node * NC + f] = vals[f] - lse;
    }
}

// ---------------------------------------------------------------------------
// GEMM3: out[N,7] = A[N,256] f32 @ W[256,7] f32. One wave per node.
// ---------------------------------------------------------------------------
__global__ __launch_bounds__(256) void gemm3_kernel(const float* __restrict__ A,
                                                    const float* __restrict__ W,
                                                    float* __restrict__ out, int n) {
    __shared__ float sW[F2 * NC];
    for (int i = threadIdx.x; i < F2 * NC; i += blockDim.x) sW[i] = W[i];
    __syncthreads();
    int gwid = (blockIdx.x * blockDim.x + threadIdx.x) >> 6;
    int lane = threadIdx.x & 63;
    if (gwid >= n) return;
    const float* row = A + (size_t)gwid * F2;
    float4 v = *(const float4*)(row + lane * 4);
    float res = 0.f;
#pragma unroll
    for (int c = 0; c < NC; ++c) {
        float p = v.x * sW[(lane * 4 + 0) * NC + c] + v.y * sW[(lane * 4 + 1) * NC + c] +
                  v.z * sW[(lane * 4 + 2) * NC + c] + v.w * sW[(lane * 4 + 3) * NC + c];
#pragma unroll
        for (int o = 32; o; o >>= 1) p += __shfl_xor(p, o);
        if (lane == c) res = p;
    }
    if (lane < NC) out[(size_t)gwid * NC + lane] = res;
}

// ---------------------------------------------------------------------------
extern "C" void kernel_launch(void* const* d_in, const int* in_sizes, int n_in,
                              void* d_out, int out_size, void* d_ws, size_t ws_size,
                              hipStream_t stream) {
    const float* x   = (const float*)d_in[0];
    const int* ei    = (const int*)d_in[1];
    const int* src   = ei;
    const int* dst   = ei + E_EDGES;
    const float* W1  = (const float*)d_in[2];
    const float* as1 = (const float*)d_in[3];
    const float* ad1 = (const float*)d_in[4];
    const float* b1  = (const float*)d_in[5];
    const float* W2  = (const float*)d_in[6];
    const float* as2 = (const float*)d_in[7];
    const float* ad2 = (const float*)d_in[8];
    const float* b2  = (const float*)d_in[9];
    const float* W3  = (const float*)d_in[10];
    const float* as3 = (const float*)d_in[11];
    const float* ad3 = (const float*)d_in[12];
    const float* b3  = (const float*)d_in[13];
    float* outp = (float*)d_out;

    // ---------------- workspace layout (byte offsets) ----------------------
    char* base = (char*)d_ws;
    u16*  a1b = (u16*)base;                                   // [N][512]  bf16
    u16*  h2b = (u16*)(base + 51200000);                      // [N][256]  bf16
    float* a2 = (float*)(base + 76800000);                    // [N][256]  f32
    float* h3 = (float*)(base + 128000000);                   // [N][7]    f32
    u16*  h1b = (u16*)(base + 144000000);                     // [N][512]  bf16
    u16*  W1t = (u16*)(base + 195200000);                     // [512][1440] bf16
    u16*  W2t = (u16*)(base + 196674560);                     // [256][512]  bf16
    float* ssrc = (float*)(base + 196936704);                 // [N]
    float* sdst = (float*)(base + 197136704);                 // [N]
    int* row_ptr = (int*)(base + 197336704);                  // [N+1]
    int* counts  = (int*)(base + 197536708);                  // [N]
    int* fill    = (int*)(base + 197736708);                  // [N]
    int* col     = (int*)(base + 197936708);                  // [E_TOT]

    hipMemsetAsync(counts, 0, sizeof(int) * N_NODES, stream);
    hipMemsetAsync(fill, 0, sizeof(int) * N_NODES, stream);

    // CSR build
    {
        int blk = 256;
        int grid = (E_TOT + blk - 1) / blk;
        count_dst_kernel<<<grid, blk, 0, stream>>>(dst, counts);
        scan_kernel<<<1, 1024, 0, stream>>>(counts, row_ptr, N_NODES);
        scatter_kernel<<<grid, blk, 0, stream>>>(src, dst, row_ptr, fill, col);
    }

    // weight bf16 conversions
    {
        int nw1 = F1 * (KPAD1 / 2);
        convert_wt_kernel<<<(nw1 + 255) / 256, 256, 0, stream>>>(W1, (u32*)W1t, F_IN, F1, KPAD1);
        int nw2 = F2 * (F1 / 2);
        convert_wt_kernel<<<(nw2 + 255) / 256, 256, 0, stream>>>(W2, (u32*)W2t, F1, F2, F1);
    }

    int waves_grid = (N_NODES + 3) / 4;
    int mblocks = (N_NODES + 127) / 128;  // 391

    // ---- Layer 1 (fused f32->bf16 conversion; x read from HBM once)
    {
        int grid1 = (N_NODES + 63) / 64;  // 782
        gemm1_fused<<<grid1, 256, 0, stream>>>(x, W1t, h1b);
        scores_bf16_kernel<F1><<<waves_grid, 256, 0, stream>>>(h1b, as1, ad1, ssrc, sdst, N_NODES);
        agg_gather_kernel<F1, true><<<N_NODES, 256, 0, stream>>>(
            h1b, ssrc, sdst, b1, row_ptr, col, a1b);
    }
    // ---- Layer 2
    {
        dim3 grid(F2 / 128, mblocks);
        mfma_gemm_bt<<<grid, 256, 0, stream>>>(a1b, W2t, h2b, N_NODES, F2, F1);
        scores_bf16_kernel<F2><<<waves_grid, 256, 0, stream>>>(h2b, as2, ad2, ssrc, sdst, N_NODES);
        agg_gather_kernel<F2, false><<<N_NODES, 256, 0, stream>>>(
            h2b, ssrc, sdst, b2, row_ptr, col, a2);
    }
    // ---- Layer 3 (fp32)
    {
        gemm3_kernel<<<waves_grid, 256, 0, stream>>>(a2, W3, h3, N_NODES);
        scores_kernel<NC><<<waves_grid, 256, 0, stream>>>(h3, as3, ad3, ssrc, sdst, N_NODES);
        agg_lsm7_kernel<<<N_NODES, 64, 0, stream>>>(
            h3, ssrc, sdst, b3, row_ptr, col, outp);
    }
}